// Round 6
// baseline (564.619 us; speedup 1.0000x reference)
//
#include <hip/hip_runtime.h>
#include <hip/hip_cooperative_groups.h>

namespace cg = cooperative_groups;

// GCN 6-layer, N=100k, E=3.2M — Krylov form.
// v = sum_{k=0..6} c_k * p_k, p_k = A_norm^k 1.
// Round 5: binA LDS-staged counting sort (coalesced chunk flush);
// one cooperative kernel for deg/dis + 6 bucket-local aggregations
// (binned-direct, no CSR) + minmax + normalize.

#define TPB 256
#define NBPAD 400        // >= nb=391 buckets
#define BINE 8192        // edges per binA block

// ---------- coefficient chain helpers (256 threads, block-level) ----------
template <int NK, int DIN>
__device__ void coef_step(const float* __restrict__ W, const float* __restrict__ bias,
                          const float (*in)[128], float (*out)[128],
                          float (*part)[6][128], int tid) {
    int t = tid & 127, half = tid >> 7;
    int i0 = half ? (DIN / 2) : 0;
    int i1 = half ? DIN : (DIN / 2);
    float s[NK];
#pragma unroll
    for (int k = 0; k < NK; ++k) s[k] = 0.f;
    if (t < 125) {
#pragma unroll 4
        for (int i = i0; i < i1; ++i) {
            float w = W[i * 125 + t];
#pragma unroll
            for (int k = 0; k < NK; ++k) s[k] += w * in[k][i];
        }
    }
#pragma unroll
    for (int k = 0; k < NK; ++k) part[half][k][t] = s[k];
    __syncthreads();
    if (half == 0 && t < 125) {
#pragma unroll
        for (int k = 0; k < NK; ++k) out[k + 1][t] = part[0][k][t] + part[1][k][t];
        out[0][t] = bias[t];
    }
    __syncthreads();
}

// ---------- merged histogram + coefficient kernel ----------
__global__ __launch_bounds__(256) void hist_coef_kernel(
    const int* __restrict__ dst, int E, int* __restrict__ bucket_cnt, int nb,
    const float* __restrict__ W1, const float* __restrict__ b1,
    const float* __restrict__ W2, const float* __restrict__ b2,
    const float* __restrict__ W3, const float* __restrict__ b3,
    const float* __restrict__ W4, const float* __restrict__ b4,
    const float* __restrict__ W5, const float* __restrict__ b5,
    const float* __restrict__ W6, const float* __restrict__ b6,
    float* __restrict__ c) {
    __shared__ int h[NBPAD];
    __shared__ float A[6][128];
    __shared__ float B[6][128];
    __shared__ float part[2][6][128];
    int t = threadIdx.x;
    int nbh = gridDim.x - 1;

    if ((int)blockIdx.x < nbh) {
        for (int j = t; j < NBPAD; j += 256) h[j] = 0;
        __syncthreads();
        for (long long e = (long long)blockIdx.x * 256 + t; e < E;
             e += (long long)nbh * 256)
            atomicAdd(&h[dst[e] >> 8], 1);
        __syncthreads();
        for (int j = t; j < nb; j += 256)
            if (h[j]) atomicAdd(&bucket_cnt[j], h[j]);
        return;
    }

    // coefficient chain
    if (t < 25) { A[1][t] = W1[t]; A[0][t] = b1[t]; }
    __syncthreads();
    coef_step<2, 25>(W2, b2, A, B, part, t);
    coef_step<3, 125>(W3, b3, B, A, part, t);
    coef_step<4, 125>(W4, b4, A, B, part, t);
    coef_step<5, 125>(W5, b5, B, A, part, t);
    int wave = t >> 6, lane = t & 63;
#pragma unroll
    for (int rep = 0; rep < 2; ++rep) {
        int k = wave + rep * 4;
        if (k < 6) {
            float acc = (lane < 125 ? W6[lane] * A[k][lane] : 0.f)
                      + (lane + 64 < 125 ? W6[lane + 64] * A[k][lane + 64] : 0.f);
            for (int off = 32; off > 0; off >>= 1) acc += __shfl_down(acc, off);
            if (lane == 0) c[k + 1] = acc;
        }
    }
    if (t == 0) c[0] = b6[0];
}

// exclusive scan of nb (<512) bucket counts; init base + cursor
__global__ void bucket_scan(const int* __restrict__ bucket_cnt, int nb,
                            int* __restrict__ bucket_base, int* __restrict__ bucket_cursor,
                            int E) {
    __shared__ int s[512];
    int t = threadIdx.x;
    int v = (t < nb) ? bucket_cnt[t] : 0;
    s[t] = v;
    __syncthreads();
    for (int off = 1; off < 512; off <<= 1) {
        int a = (t >= off) ? s[t - off] : 0;
        __syncthreads();
        s[t] += a;
        __syncthreads();
    }
    if (t < nb) {
        int ex = s[t] - v;
        bucket_base[t] = ex;
        bucket_cursor[t] = ex;
    }
    if (t == 0) bucket_base[nb] = E;
}

// ---------- binA: LDS-staged counting sort per 8192-edge block ----------
// binned word: (dst&255)<<24 | src   (src < 2^24)
__global__ __launch_bounds__(256) void binA_kernel(
    const int* __restrict__ src, const int* __restrict__ dst, int E,
    int* __restrict__ bucket_cursor, unsigned int* __restrict__ binned) {
    __shared__ int cnt[NBPAD];
    __shared__ int sa[512], sb[512];
    __shared__ int lbase[NBPAD];
    __shared__ int gbase[NBPAD];
    __shared__ int lcur[NBPAD];
    __shared__ unsigned int stagew[BINE];
    __shared__ unsigned short sbuck[BINE];
    int t = threadIdx.x;
    long long base = (long long)blockIdx.x * BINE;
    int ne = (E - base < BINE) ? (int)(E - base) : BINE;

    for (int j = t; j < NBPAD; j += 256) cnt[j] = 0;
    __syncthreads();
    for (int j = t; j < ne; j += 256) atomicAdd(&cnt[dst[base + j] >> 8], 1);
    __syncthreads();
    // Kogge-Stone inclusive scan over 512 (ping-pong)
    for (int j = t; j < 512; j += 256) sa[j] = (j < NBPAD) ? cnt[j] : 0;
    __syncthreads();
    int* cu = sa; int* nx = sb;
    for (int off = 1; off < 512; off <<= 1) {
        for (int j = t; j < 512; j += 256) nx[j] = cu[j] + (j >= off ? cu[j - off] : 0);
        __syncthreads();
        int* tmp = cu; cu = nx; nx = tmp;
    }
    for (int j = t; j < NBPAD; j += 256) {
        int ex = cu[j] - cnt[j];
        lbase[j] = ex;
        lcur[j] = ex;
        gbase[j] = cnt[j] ? atomicAdd(&bucket_cursor[j], cnt[j]) : 0;
    }
    __syncthreads();
    // stage (bucket-sorted within block)
    for (int j = t; j < ne; j += 256) {
        int dv = dst[base + j];
        int sv = src[base + j];
        int bk = dv >> 8;
        int pos = atomicAdd(&lcur[bk], 1);
        stagew[pos] = ((unsigned)(dv & 255) << 24) | (unsigned)sv;
        sbuck[pos] = (unsigned short)bk;
    }
    __syncthreads();
    // coalesced chunk flush
    for (int j = t; j < ne; j += 256) {
        int bk = sbuck[j];
        binned[gbase[bk] + (j - lbase[bk])] = stagew[j];
    }
}

// ---------- cooperative: deg/dis + 6 aggregations + minmax + normalize ----------
// one block per 256-node bucket, 512 threads; threads t<256 own node (b<<8)+t
__global__ __launch_bounds__(512) void coop_kernel(
    const unsigned int* __restrict__ binned, const int* __restrict__ bucket_base,
    int nb, int n,
    float* __restrict__ dis, float* __restrict__ qA, float* __restrict__ qB,
    const float* __restrict__ c,
    float* __restrict__ bmin, float* __restrict__ bmax, float* __restrict__ out) {
    cg::grid_group grid = cg::this_grid();
    __shared__ float accs[256];
    __shared__ int degs[256];
    __shared__ float smn[512], smx[512];
    int b = blockIdx.x;
    int t = threadIdx.x;
    int ebase = bucket_base[b], eend = bucket_base[b + 1];
    int gnode = (b << 8) + (t & 255);
    bool owner = (t < 256) && (gnode < n);

    float cc[7];
#pragma unroll
    for (int k = 0; k < 7; ++k) cc[k] = c[k];

    // phase 0: degree -> dis
    if (t < 256) degs[t] = 0;
    __syncthreads();
    for (int e = ebase + t; e < eend; e += 512)
        atomicAdd(&degs[binned[e] >> 24], 1);
    __syncthreads();
    float d = 0.f, qown = 0.f, vacc = 0.f;
    if (owner) {
        d = rsqrtf((float)degs[t] + 1.0f);   // +1 = self-loop
        dis[gnode] = d;
        qown = d;                            // q0 = dis .* ones
        vacc = cc[0];
    }
    grid.sync();

    // 6 aggregation iterations
    const float* q = dis;
    for (int k = 1; k <= 6; ++k) {
        float* qn = (k & 1) ? qA : qB;
        if (t < 256) accs[t] = 0.f;
        __syncthreads();
        for (int e = ebase + t; e < eend; e += 512) {
            unsigned int pk = binned[e];
            atomicAdd(&accs[pk >> 24], q[pk & 0xffffffu]);
        }
        __syncthreads();
        if (owner) {
            float p = d * (accs[t] + qown);
            qown = d * p;
            qn[gnode] = qown;
            vacc += cc[k] * p;
        }
        grid.sync();
        q = qn;
    }

    // block-local min/max partials
    smn[t] = owner ? vacc : 1e30f;
    smx[t] = owner ? vacc : -1e30f;
    __syncthreads();
    for (int s = 256; s > 0; s >>= 1) {
        if (t < s) {
            smn[t] = fminf(smn[t], smn[t + s]);
            smx[t] = fmaxf(smx[t], smx[t + s]);
        }
        __syncthreads();
    }
    if (t == 0) { bmin[b] = smn[0]; bmax[b] = smx[0]; }
    grid.sync();

    // redundant per-block final reduce + normalize
    float mn = 1e30f, mx = -1e30f;
    for (int j = t; j < nb; j += 512) {
        mn = fminf(mn, bmin[j]);
        mx = fmaxf(mx, bmax[j]);
    }
    smn[t] = mn; smx[t] = mx;
    __syncthreads();
    for (int s = 256; s > 0; s >>= 1) {
        if (t < s) {
            smn[t] = fminf(smn[t], smn[t + s]);
            smx[t] = fmaxf(smx[t], smx[t + s]);
        }
        __syncthreads();
    }
    mn = smn[0]; mx = smx[0];
    if (owner) out[gnode] = (vacc - mn) / (mx - mn + 1e-15f);
}

static inline int cdiv(long long a, int b) { return (int)((a + b - 1) / b); }

extern "C" void kernel_launch(void* const* d_in, const int* in_sizes, int n_in,
                              void* d_out, int out_size, void* d_ws, size_t ws_size,
                              hipStream_t stream) {
    const int N = out_size;               // 100000
    const int E = in_sizes[0] / 2;        // 3200000
    const int* src = (const int*)d_in[0];
    const int* dst = src + E;

    const float* W1 = (const float*)d_in[1];  const float* b1 = (const float*)d_in[2];
    const float* W2 = (const float*)d_in[3];  const float* b2 = (const float*)d_in[4];
    const float* W3 = (const float*)d_in[5];  const float* b3 = (const float*)d_in[6];
    const float* W4 = (const float*)d_in[7];  const float* b4 = (const float*)d_in[8];
    const float* W5 = (const float*)d_in[9];  const float* b5 = (const float*)d_in[10];
    const float* W6 = (const float*)d_in[11]; const float* b6 = (const float*)d_in[12];

    const int nb = (N + 255) >> 8;        // 391 buckets of 256 nodes

    // workspace layout
    char* p = (char*)d_ws;
    int*   bucket_cnt    = (int*)p;   p += (size_t)512 * 4;
    int*   bucket_base   = (int*)p;   p += (size_t)512 * 4;
    int*   bucket_cursor = (int*)p;   p += (size_t)512 * 4;
    unsigned int* binned = (unsigned int*)p; p += (size_t)E * 4;
    float* dis    = (float*)p; p += (size_t)N * 4;
    float* qA     = (float*)p; p += (size_t)N * 4;
    float* qB     = (float*)p; p += (size_t)N * 4;
    float* c      = (float*)p; p += (size_t)8 * 4;
    float* bmin   = (float*)p; p += (size_t)512 * 4;
    float* bmax   = (float*)p; p += (size_t)512 * 4;

    // ---- CSR-less build: hist(+coef), scan, LDS-staged binning ----
    hipMemsetAsync(bucket_cnt, 0, 512 * 4, stream);
    hist_coef_kernel<<<513, 256, 0, stream>>>(dst, E, bucket_cnt, nb,
                                              W1, b1, W2, b2, W3, b3,
                                              W4, b4, W5, b5, W6, b6, c);
    bucket_scan<<<1, 512, 0, stream>>>(bucket_cnt, nb, bucket_base, bucket_cursor, E);
    binA_kernel<<<cdiv(E, BINE), 256, 0, stream>>>(src, dst, E, bucket_cursor, binned);

    // ---- cooperative: everything else in one launch ----
    {
        const unsigned int* binned_c = binned;
        const int* bb = bucket_base;
        const float* cc = c;
        float* outp = (float*)d_out;
        int nb_ = nb, n_ = N;
        float *dis_ = dis, *qA_ = qA, *qB_ = qB, *bmin_ = bmin, *bmax_ = bmax;
        void* args[] = { &binned_c, &bb, &nb_, &n_, &dis_, &qA_, &qB_,
                         &cc, &bmin_, &bmax_, &outp };
        hipLaunchCooperativeKernel((const void*)coop_kernel, dim3(nb), dim3(512),
                                   args, 0, stream);
    }
}

// Round 7
// 203.624 us; speedup vs baseline: 2.7729x; 2.7729x over previous
//
#include <hip/hip_runtime.h>

// GCN 6-layer, N=100k, E=3.2M — Krylov form + binned CSR build.
// v = sum_{k=0..6} c_k * p_k, p_k = A_norm^k 1.
// Round 6: revert cooperative aggregation (round-5 regression) back to
// node-parallel gather_step chain; keep LDS-staged binA (coalesced flush).

#define TPB 256
#define NBPAD 400        // >= nb=391 buckets
#define BINE 8192        // edges per binA block
#define STAGE_CAP 12288  // per-bucket csr LDS stage (mean 8192, sigma ~90)

// ---------- coefficient chain helpers (256 threads, block-level) ----------
template <int NK, int DIN>
__device__ void coef_step(const float* __restrict__ W, const float* __restrict__ bias,
                          const float (*in)[128], float (*out)[128],
                          float (*part)[6][128], int tid) {
    int t = tid & 127, half = tid >> 7;
    int i0 = half ? (DIN / 2) : 0;
    int i1 = half ? DIN : (DIN / 2);
    float s[NK];
#pragma unroll
    for (int k = 0; k < NK; ++k) s[k] = 0.f;
    if (t < 125) {
#pragma unroll 4
        for (int i = i0; i < i1; ++i) {
            float w = W[i * 125 + t];
#pragma unroll
            for (int k = 0; k < NK; ++k) s[k] += w * in[k][i];
        }
    }
#pragma unroll
    for (int k = 0; k < NK; ++k) part[half][k][t] = s[k];
    __syncthreads();
    if (half == 0 && t < 125) {
#pragma unroll
        for (int k = 0; k < NK; ++k) out[k + 1][t] = part[0][k][t] + part[1][k][t];
        out[0][t] = bias[t];
    }
    __syncthreads();
}

// ---------- merged histogram + coefficient kernel ----------
__global__ __launch_bounds__(256) void hist_coef_kernel(
    const int* __restrict__ dst, int E, int* __restrict__ bucket_cnt, int nb,
    const float* __restrict__ W1, const float* __restrict__ b1,
    const float* __restrict__ W2, const float* __restrict__ b2,
    const float* __restrict__ W3, const float* __restrict__ b3,
    const float* __restrict__ W4, const float* __restrict__ b4,
    const float* __restrict__ W5, const float* __restrict__ b5,
    const float* __restrict__ W6, const float* __restrict__ b6,
    float* __restrict__ c) {
    __shared__ int h[NBPAD];
    __shared__ float A[6][128];
    __shared__ float B[6][128];
    __shared__ float part[2][6][128];
    int t = threadIdx.x;
    int nbh = gridDim.x - 1;

    if ((int)blockIdx.x < nbh) {
        for (int j = t; j < NBPAD; j += 256) h[j] = 0;
        __syncthreads();
        for (long long e = (long long)blockIdx.x * 256 + t; e < E;
             e += (long long)nbh * 256)
            atomicAdd(&h[dst[e] >> 8], 1);
        __syncthreads();
        for (int j = t; j < nb; j += 256)
            if (h[j]) atomicAdd(&bucket_cnt[j], h[j]);
        return;
    }

    // coefficient chain
    if (t < 25) { A[1][t] = W1[t]; A[0][t] = b1[t]; }
    __syncthreads();
    coef_step<2, 25>(W2, b2, A, B, part, t);
    coef_step<3, 125>(W3, b3, B, A, part, t);
    coef_step<4, 125>(W4, b4, A, B, part, t);
    coef_step<5, 125>(W5, b5, B, A, part, t);
    int wave = t >> 6, lane = t & 63;
#pragma unroll
    for (int rep = 0; rep < 2; ++rep) {
        int k = wave + rep * 4;
        if (k < 6) {
            float acc = (lane < 125 ? W6[lane] * A[k][lane] : 0.f)
                      + (lane + 64 < 125 ? W6[lane + 64] * A[k][lane + 64] : 0.f);
            for (int off = 32; off > 0; off >>= 1) acc += __shfl_down(acc, off);
            if (lane == 0) c[k + 1] = acc;
        }
    }
    if (t == 0) c[0] = b6[0];
}

// exclusive scan of nb (<512) bucket counts; init base + cursor; rowptr[n]=E
__global__ void bucket_scan(const int* __restrict__ bucket_cnt, int nb,
                            int* __restrict__ bucket_base, int* __restrict__ bucket_cursor,
                            int* __restrict__ rowptr, int n, int E) {
    __shared__ int s[512];
    int t = threadIdx.x;
    int v = (t < nb) ? bucket_cnt[t] : 0;
    s[t] = v;
    __syncthreads();
    for (int off = 1; off < 512; off <<= 1) {
        int a = (t >= off) ? s[t - off] : 0;
        __syncthreads();
        s[t] += a;
        __syncthreads();
    }
    if (t < nb) {
        int ex = s[t] - v;
        bucket_base[t] = ex;
        bucket_cursor[t] = ex;
    }
    if (t == 0) { bucket_base[nb] = E; rowptr[n] = E; }
}

// ---------- binA: LDS-staged counting sort per 8192-edge block ----------
// binned word: (dst&255)<<24 | src   (src < 2^24)
__global__ __launch_bounds__(256) void binA_kernel(
    const int* __restrict__ src, const int* __restrict__ dst, int E,
    int* __restrict__ bucket_cursor, unsigned int* __restrict__ binned) {
    __shared__ int cnt[NBPAD];
    __shared__ int sa[512], sb[512];
    __shared__ int lbase[NBPAD];
    __shared__ int gbase[NBPAD];
    __shared__ int lcur[NBPAD];
    __shared__ unsigned int stagew[BINE];
    __shared__ unsigned short sbuck[BINE];
    int t = threadIdx.x;
    long long base = (long long)blockIdx.x * BINE;
    int ne = (E - base < BINE) ? (int)(E - base) : BINE;

    for (int j = t; j < NBPAD; j += 256) cnt[j] = 0;
    __syncthreads();
    for (int j = t; j < ne; j += 256) atomicAdd(&cnt[dst[base + j] >> 8], 1);
    __syncthreads();
    // Kogge-Stone inclusive scan over 512 (ping-pong)
    for (int j = t; j < 512; j += 256) sa[j] = (j < NBPAD) ? cnt[j] : 0;
    __syncthreads();
    int* cu = sa; int* nx = sb;
    for (int off = 1; off < 512; off <<= 1) {
        for (int j = t; j < 512; j += 256) nx[j] = cu[j] + (j >= off ? cu[j - off] : 0);
        __syncthreads();
        int* tmp = cu; cu = nx; nx = tmp;
    }
    for (int j = t; j < NBPAD; j += 256) {
        int ex = cu[j] - cnt[j];
        lbase[j] = ex;
        lcur[j] = ex;
        gbase[j] = cnt[j] ? atomicAdd(&bucket_cursor[j], cnt[j]) : 0;
    }
    __syncthreads();
    // stage (bucket-sorted within block)
    for (int j = t; j < ne; j += 256) {
        int dv = dst[base + j];
        int sv = src[base + j];
        int bk = dv >> 8;
        int pos = atomicAdd(&lcur[bk], 1);
        stagew[pos] = ((unsigned)(dv & 255) << 24) | (unsigned)sv;
        sbuck[pos] = (unsigned short)bk;
    }
    __syncthreads();
    // coalesced chunk flush
    for (int j = t; j < ne; j += 256) {
        int bk = sbuck[j];
        binned[gbase[bk] + (j - lbase[bk])] = stagew[j];
    }
}

// ---------- csrB: one block per bucket -> rowptr, dis, node-sorted csr ----------
__global__ __launch_bounds__(256) void csrB_kernel(
    const unsigned int* __restrict__ binned,
    const int* __restrict__ bucket_base, int n,
    int* __restrict__ rowptr, int* __restrict__ csr, float* __restrict__ dis) {
    __shared__ int deg[256];
    __shared__ int ex[256];
    __shared__ int cur[256];
    __shared__ int stage[STAGE_CAP];
    int b = blockIdx.x;
    int t = threadIdx.x;
    int ebase = bucket_base[b], eend = bucket_base[b + 1];
    int esize = eend - ebase;
    int gnode = (b << 8) + t;
    deg[t] = 0;
    __syncthreads();
    for (int e = ebase + t; e < eend; e += 256)
        atomicAdd(&deg[binned[e] >> 24], 1);
    __syncthreads();
    int d = deg[t];
    ex[t] = d;
    __syncthreads();
    for (int off = 1; off < 256; off <<= 1) {
        int a = (t >= off) ? ex[t - off] : 0;
        __syncthreads();
        ex[t] += a;
        __syncthreads();
    }
    int excl = ex[t] - d;
    if (gnode < n) {
        rowptr[gnode] = ebase + excl;
        dis[gnode] = rsqrtf((float)d + 1.0f);   // +1 = self-loop
    }
    cur[t] = excl;
    __syncthreads();
    if (esize <= STAGE_CAP) {
        for (int e = ebase + t; e < eend; e += 256) {
            unsigned int pk = binned[e];
            int pos = atomicAdd(&cur[pk >> 24], 1);
            stage[pos] = (int)(pk & 0xffffffu);
        }
        __syncthreads();
        for (int e = t; e < esize; e += 256) csr[ebase + e] = stage[e];
    } else {  // statistical-impossibility fallback, keeps any input correct
        for (int e = ebase + t; e < eend; e += 256) {
            unsigned int pk = binned[e];
            int pos = atomicAdd(&cur[pk >> 24], 1);
            csr[ebase + pos] = (int)(pk & 0xffffffu);
        }
    }
}

// ---------- scalar aggregation step ----------
__global__ void gather_step(const int* __restrict__ rowptr, const int* __restrict__ csr,
                            const float* __restrict__ dis, const float* __restrict__ q,
                            const float* __restrict__ c, int k,
                            float* __restrict__ qnext, float* __restrict__ vacc,
                            int n, int first) {
    int tid = blockIdx.x * blockDim.x + threadIdx.x;
    int node = tid >> 4;
    int lane = tid & 15;
    if (node >= n) return;
    int beg = rowptr[node], end = rowptr[node + 1];
    float acc = 0.f;
    for (int e = beg + lane; e < end; e += 16) acc += q[csr[e]];
    for (int off = 8; off > 0; off >>= 1) acc += __shfl_down(acc, off, 16);
    if (lane == 0) {
        float d = dis[node];
        float p = d * (acc + q[node]);
        qnext[node] = d * p;
        float add = c[k] * p;
        vacc[node] = first ? (c[0] + add) : (vacc[node] + add);
    }
}

// ---------- min-max normalize ----------
__global__ void minmax_part_kernel(const float* __restrict__ v, int n,
                                   float* __restrict__ bmin, float* __restrict__ bmax) {
    __shared__ float smn[TPB], smx[TPB];
    int t = threadIdx.x;
    float mn = 1e30f, mx = -1e30f;
    for (int i = blockIdx.x * blockDim.x + t; i < n; i += gridDim.x * blockDim.x) {
        float x = v[i];
        mn = fminf(mn, x);
        mx = fmaxf(mx, x);
    }
    smn[t] = mn; smx[t] = mx;
    __syncthreads();
    for (int s = TPB / 2; s > 0; s >>= 1) {
        if (t < s) { smn[t] = fminf(smn[t], smn[t + s]); smx[t] = fmaxf(smx[t], smx[t + s]); }
        __syncthreads();
    }
    if (t == 0) { bmin[blockIdx.x] = smn[0]; bmax[blockIdx.x] = smx[0]; }
}

__global__ void minmax_final_kernel(const float* __restrict__ bmin, const float* __restrict__ bmax,
                                    int nblk, float* __restrict__ mnmx) {
    __shared__ float smn[TPB], smx[TPB];
    int t = threadIdx.x;
    float mn = 1e30f, mx = -1e30f;
    for (int i = t; i < nblk; i += TPB) {
        mn = fminf(mn, bmin[i]);
        mx = fmaxf(mx, bmax[i]);
    }
    smn[t] = mn; smx[t] = mx;
    __syncthreads();
    for (int s = TPB / 2; s > 0; s >>= 1) {
        if (t < s) { smn[t] = fminf(smn[t], smn[t + s]); smx[t] = fmaxf(smx[t], smx[t + s]); }
        __syncthreads();
    }
    if (t == 0) { mnmx[0] = smn[0]; mnmx[1] = smx[0]; }
}

__global__ void normalize_kernel(const float* __restrict__ v, const float* __restrict__ mnmx,
                                 float* __restrict__ out, int n) {
    int i = blockIdx.x * blockDim.x + threadIdx.x;
    if (i < n) {
        float mn = mnmx[0], mx = mnmx[1];
        out[i] = (v[i] - mn) / (mx - mn + 1e-15f);
    }
}

static inline int cdiv(long long a, int b) { return (int)((a + b - 1) / b); }

extern "C" void kernel_launch(void* const* d_in, const int* in_sizes, int n_in,
                              void* d_out, int out_size, void* d_ws, size_t ws_size,
                              hipStream_t stream) {
    const int N = out_size;               // 100000
    const int E = in_sizes[0] / 2;        // 3200000
    const int* src = (const int*)d_in[0];
    const int* dst = src + E;

    const float* W1 = (const float*)d_in[1];  const float* b1 = (const float*)d_in[2];
    const float* W2 = (const float*)d_in[3];  const float* b2 = (const float*)d_in[4];
    const float* W3 = (const float*)d_in[5];  const float* b3 = (const float*)d_in[6];
    const float* W4 = (const float*)d_in[7];  const float* b4 = (const float*)d_in[8];
    const float* W5 = (const float*)d_in[9];  const float* b5 = (const float*)d_in[10];
    const float* W6 = (const float*)d_in[11]; const float* b6 = (const float*)d_in[12];

    const int nb = (N + 255) >> 8;        // 391 buckets of 256 nodes

    // workspace layout
    char* p = (char*)d_ws;
    int*   bucket_cnt    = (int*)p;   p += (size_t)512 * 4;
    int*   bucket_base   = (int*)p;   p += (size_t)512 * 4;
    int*   bucket_cursor = (int*)p;   p += (size_t)512 * 4;
    int*   rowptr        = (int*)p;   p += (size_t)(N + 1) * 4;
    int*   csr           = (int*)p;   p += (size_t)E * 4;
    unsigned int* binned = (unsigned int*)p; p += (size_t)E * 4;
    float* dis    = (float*)p; p += (size_t)N * 4;
    float* qA     = (float*)p; p += (size_t)N * 4;
    float* qB     = (float*)p; p += (size_t)N * 4;
    float* vacc   = (float*)p; p += (size_t)N * 4;
    float* c      = (float*)p; p += (size_t)8 * 4;
    float* bmin   = (float*)p; p += (size_t)TPB * 4;
    float* bmax   = (float*)p; p += (size_t)TPB * 4;
    float* mnmx   = (float*)p; p += 2 * 4;

    // ---- CSR build + coefficients (coef hidden in hist launch) ----
    hipMemsetAsync(bucket_cnt, 0, 512 * 4, stream);
    hist_coef_kernel<<<513, 256, 0, stream>>>(dst, E, bucket_cnt, nb,
                                              W1, b1, W2, b2, W3, b3,
                                              W4, b4, W5, b5, W6, b6, c);
    bucket_scan<<<1, 512, 0, stream>>>(bucket_cnt, nb, bucket_base, bucket_cursor,
                                       rowptr, N, E);
    binA_kernel<<<cdiv(E, BINE), 256, 0, stream>>>(src, dst, E, bucket_cursor, binned);
    csrB_kernel<<<nb, 256, 0, stream>>>(binned, bucket_base, N, rowptr, csr, dis);

    // ---- 6 scalar aggregations ----
    const int gblocks = cdiv((long long)N * 16, TPB);
    gather_step<<<gblocks, TPB, 0, stream>>>(rowptr, csr, dis, dis, c, 1, qA, vacc, N, 1);
    gather_step<<<gblocks, TPB, 0, stream>>>(rowptr, csr, dis, qA,  c, 2, qB, vacc, N, 0);
    gather_step<<<gblocks, TPB, 0, stream>>>(rowptr, csr, dis, qB,  c, 3, qA, vacc, N, 0);
    gather_step<<<gblocks, TPB, 0, stream>>>(rowptr, csr, dis, qA,  c, 4, qB, vacc, N, 0);
    gather_step<<<gblocks, TPB, 0, stream>>>(rowptr, csr, dis, qB,  c, 5, qA, vacc, N, 0);
    gather_step<<<gblocks, TPB, 0, stream>>>(rowptr, csr, dis, qA,  c, 6, qB, vacc, N, 0);

    // ---- min-max normalize ----
    minmax_part_kernel<<<TPB, TPB, 0, stream>>>(vacc, N, bmin, bmax);
    minmax_final_kernel<<<1, TPB, 0, stream>>>(bmin, bmax, TPB, mnmx);
    normalize_kernel<<<cdiv(N, TPB), TPB, 0, stream>>>(vacc, mnmx, (float*)d_out, N);
}

// Round 9
// 201.573 us; speedup vs baseline: 2.8011x; 1.0102x over previous
//
#include <hip/hip_runtime.h>

// GCN 6-layer, N=100k, E=3.2M — Krylov form + binned CSR build.
// v = sum_{k=0..6} c_k * p_k, p_k = A_norm^k 1.
// Round 8: round-6 structure (passing) + int4 hist + int4 reg-cached binA +
// fused (gather k=6 + minmax partials). Cooperative gather dropped: round-7
// fail was an occupancy-infeasible cooperative launch (silent no-op).

#define TPB 256
#define NBPAD 400        // >= nb=391 buckets
#define BINE 8192        // edges per binA block
#define STAGE_CAP 12288  // per-bucket csr LDS stage (mean 8192, sigma ~90)

// ---------- coefficient chain helpers (256 threads, block-level) ----------
template <int NK, int DIN>
__device__ void coef_step(const float* __restrict__ W, const float* __restrict__ bias,
                          const float (*in)[128], float (*out)[128],
                          float (*part)[6][128], int tid) {
    int t = tid & 127, half = tid >> 7;
    int i0 = half ? (DIN / 2) : 0;
    int i1 = half ? DIN : (DIN / 2);
    float s[NK];
#pragma unroll
    for (int k = 0; k < NK; ++k) s[k] = 0.f;
    if (t < 125) {
#pragma unroll 4
        for (int i = i0; i < i1; ++i) {
            float w = W[i * 125 + t];
#pragma unroll
            for (int k = 0; k < NK; ++k) s[k] += w * in[k][i];
        }
    }
#pragma unroll
    for (int k = 0; k < NK; ++k) part[half][k][t] = s[k];
    __syncthreads();
    if (half == 0 && t < 125) {
#pragma unroll
        for (int k = 0; k < NK; ++k) out[k + 1][t] = part[0][k][t] + part[1][k][t];
        out[0][t] = bias[t];
    }
    __syncthreads();
}

// ---------- merged histogram + coefficient kernel ----------
__global__ __launch_bounds__(256) void hist_coef_kernel(
    const int* __restrict__ dst, int E, int* __restrict__ bucket_cnt, int nb,
    const float* __restrict__ W1, const float* __restrict__ b1,
    const float* __restrict__ W2, const float* __restrict__ b2,
    const float* __restrict__ W3, const float* __restrict__ b3,
    const float* __restrict__ W4, const float* __restrict__ b4,
    const float* __restrict__ W5, const float* __restrict__ b5,
    const float* __restrict__ W6, const float* __restrict__ b6,
    float* __restrict__ c) {
    __shared__ int h[NBPAD];
    __shared__ float A[6][128];
    __shared__ float B[6][128];
    __shared__ float part[2][6][128];
    int t = threadIdx.x;
    int nbh = gridDim.x - 1;

    if ((int)blockIdx.x < nbh) {
        for (int j = t; j < NBPAD; j += 256) h[j] = 0;
        __syncthreads();
        const int E4 = E >> 2;
        const int chunk4 = (E4 + nbh - 1) / nbh;
        const int b4 = (int)blockIdx.x * chunk4;
        const int e4 = (b4 + chunk4 < E4) ? (b4 + chunk4) : E4;
        const int4* d4 = (const int4*)dst;
        for (int j = b4 + t; j < e4; j += 256) {
            int4 v = d4[j];
            atomicAdd(&h[v.x >> 8], 1);
            atomicAdd(&h[v.y >> 8], 1);
            atomicAdd(&h[v.z >> 8], 1);
            atomicAdd(&h[v.w >> 8], 1);
        }
        if (blockIdx.x == 0) {  // scalar tail (E % 4)
            for (int j = (E4 << 2) + t; j < E; j += 256) atomicAdd(&h[dst[j] >> 8], 1);
        }
        __syncthreads();
        for (int j = t; j < nb; j += 256)
            if (h[j]) atomicAdd(&bucket_cnt[j], h[j]);
        return;
    }

    // coefficient chain
    if (t < 25) { A[1][t] = W1[t]; A[0][t] = b1[t]; }
    __syncthreads();
    coef_step<2, 25>(W2, b2, A, B, part, t);
    coef_step<3, 125>(W3, b3, B, A, part, t);
    coef_step<4, 125>(W4, b4, A, B, part, t);
    coef_step<5, 125>(W5, b5, B, A, part, t);
    int wave = t >> 6, lane = t & 63;
#pragma unroll
    for (int rep = 0; rep < 2; ++rep) {
        int k = wave + rep * 4;
        if (k < 6) {
            float acc = (lane < 125 ? W6[lane] * A[k][lane] : 0.f)
                      + (lane + 64 < 125 ? W6[lane + 64] * A[k][lane + 64] : 0.f);
            for (int off = 32; off > 0; off >>= 1) acc += __shfl_down(acc, off);
            if (lane == 0) c[k + 1] = acc;
        }
    }
    if (t == 0) c[0] = b6[0];
}

// exclusive scan of nb (<512) bucket counts; init base + cursor; rowptr[n]=E
__global__ void bucket_scan(const int* __restrict__ bucket_cnt, int nb,
                            int* __restrict__ bucket_base, int* __restrict__ bucket_cursor,
                            int* __restrict__ rowptr, int n, int E) {
    __shared__ int s[512];
    int t = threadIdx.x;
    int v = (t < nb) ? bucket_cnt[t] : 0;
    s[t] = v;
    __syncthreads();
    for (int off = 1; off < 512; off <<= 1) {
        int a = (t >= off) ? s[t - off] : 0;
        __syncthreads();
        s[t] += a;
        __syncthreads();
    }
    if (t < nb) {
        int ex = s[t] - v;
        bucket_base[t] = ex;
        bucket_cursor[t] = ex;
    }
    if (t == 0) { bucket_base[nb] = E; rowptr[n] = E; }
}

// ---------- binA: LDS-staged counting sort per 8192-edge block ----------
// binned word: (dst&255)<<24 | src   (src < 2^24)
__global__ __launch_bounds__(256) void binA_kernel(
    const int* __restrict__ src, const int* __restrict__ dst, int E,
    int* __restrict__ bucket_cursor, unsigned int* __restrict__ binned) {
    __shared__ int cnt[NBPAD];
    __shared__ int sa[512], sb[512];
    __shared__ int lbase[NBPAD];
    __shared__ int gbase[NBPAD];
    __shared__ int lcur[NBPAD];
    __shared__ unsigned int stagew[BINE];
    __shared__ unsigned short sbuck[BINE];
    int t = threadIdx.x;
    long long base = (long long)blockIdx.x * BINE;
    int ne = (E - base < BINE) ? (int)(E - base) : BINE;

    for (int j = t; j < NBPAD; j += 256) cnt[j] = 0;
    __syncthreads();

    // count phase: int4 loads, dst cached in registers
    int dv[8][4];
    const int4* d4 = (const int4*)(dst + base);
#pragma unroll
    for (int i = 0; i < 8; ++i) {
        int j4 = t + i * 256;
        if ((j4 << 2) + 3 < ne) {
            int4 v = d4[j4];
            dv[i][0] = v.x; dv[i][1] = v.y; dv[i][2] = v.z; dv[i][3] = v.w;
        } else {
#pragma unroll
            for (int cx = 0; cx < 4; ++cx) {
                int j = (j4 << 2) + cx;
                dv[i][cx] = (j < ne) ? dst[base + j] : -1;
            }
        }
#pragma unroll
        for (int cx = 0; cx < 4; ++cx)
            if (dv[i][cx] >= 0) atomicAdd(&cnt[dv[i][cx] >> 8], 1);
    }
    __syncthreads();
    // Kogge-Stone inclusive scan over 512 (ping-pong)
    for (int j = t; j < 512; j += 256) sa[j] = (j < NBPAD) ? cnt[j] : 0;
    __syncthreads();
    int* cu = sa; int* nx = sb;
    for (int off = 1; off < 512; off <<= 1) {
        for (int j = t; j < 512; j += 256) nx[j] = cu[j] + (j >= off ? cu[j - off] : 0);
        __syncthreads();
        int* tmp = cu; cu = nx; nx = tmp;
    }
    for (int j = t; j < NBPAD; j += 256) {
        int ex = cu[j] - cnt[j];
        lbase[j] = ex;
        lcur[j] = ex;
        gbase[j] = cnt[j] ? atomicAdd(&bucket_cursor[j], cnt[j]) : 0;
    }
    __syncthreads();
    // stage phase: int4 src loads, dst from registers
    const int4* s4 = (const int4*)(src + base);
#pragma unroll
    for (int i = 0; i < 8; ++i) {
        int j4 = t + i * 256;
        int sv[4];
        if ((j4 << 2) + 3 < ne) {
            int4 v = s4[j4];
            sv[0] = v.x; sv[1] = v.y; sv[2] = v.z; sv[3] = v.w;
        } else {
#pragma unroll
            for (int cx = 0; cx < 4; ++cx) {
                int j = (j4 << 2) + cx;
                sv[cx] = (j < ne) ? src[base + j] : -1;
            }
        }
#pragma unroll
        for (int cx = 0; cx < 4; ++cx) {
            if (dv[i][cx] >= 0) {
                int bk = dv[i][cx] >> 8;
                int pos = atomicAdd(&lcur[bk], 1);
                stagew[pos] = ((unsigned)(dv[i][cx] & 255) << 24) | (unsigned)sv[cx];
                sbuck[pos] = (unsigned short)bk;
            }
        }
    }
    __syncthreads();
    // coalesced chunk flush
    for (int j = t; j < ne; j += 256) {
        int bk = sbuck[j];
        binned[gbase[bk] + (j - lbase[bk])] = stagew[j];
    }
}

// ---------- csrB: one block per bucket -> rowptr, dis, node-sorted csr ----------
__global__ __launch_bounds__(256) void csrB_kernel(
    const unsigned int* __restrict__ binned,
    const int* __restrict__ bucket_base, int n,
    int* __restrict__ rowptr, int* __restrict__ csr, float* __restrict__ dis) {
    __shared__ int deg[256];
    __shared__ int ex[256];
    __shared__ int cur[256];
    __shared__ int stage[STAGE_CAP];
    int b = blockIdx.x;
    int t = threadIdx.x;
    int ebase = bucket_base[b], eend = bucket_base[b + 1];
    int esize = eend - ebase;
    int gnode = (b << 8) + t;
    deg[t] = 0;
    __syncthreads();
    for (int e = ebase + t; e < eend; e += 256)
        atomicAdd(&deg[binned[e] >> 24], 1);
    __syncthreads();
    int d = deg[t];
    ex[t] = d;
    __syncthreads();
    for (int off = 1; off < 256; off <<= 1) {
        int a = (t >= off) ? ex[t - off] : 0;
        __syncthreads();
        ex[t] += a;
        __syncthreads();
    }
    int excl = ex[t] - d;
    if (gnode < n) {
        rowptr[gnode] = ebase + excl;
        dis[gnode] = rsqrtf((float)d + 1.0f);   // +1 = self-loop
    }
    cur[t] = excl;
    __syncthreads();
    if (esize <= STAGE_CAP) {
        for (int e = ebase + t; e < eend; e += 256) {
            unsigned int pk = binned[e];
            int pos = atomicAdd(&cur[pk >> 24], 1);
            stage[pos] = (int)(pk & 0xffffffu);
        }
        __syncthreads();
        for (int e = t; e < esize; e += 256) csr[ebase + e] = stage[e];
    } else {  // statistical-impossibility fallback, keeps any input correct
        for (int e = ebase + t; e < eend; e += 256) {
            unsigned int pk = binned[e];
            int pos = atomicAdd(&cur[pk >> 24], 1);
            csr[ebase + pos] = (int)(pk & 0xffffffu);
        }
    }
}

// ---------- scalar aggregation step ----------
__global__ void gather_step(const int* __restrict__ rowptr, const int* __restrict__ csr,
                            const float* __restrict__ dis, const float* __restrict__ q,
                            const float* __restrict__ c, int k,
                            float* __restrict__ qnext, float* __restrict__ vacc,
                            int n, int first) {
    int tid = blockIdx.x * blockDim.x + threadIdx.x;
    int node = tid >> 4;
    int lane = tid & 15;
    if (node >= n) return;
    int beg = rowptr[node], end = rowptr[node + 1];
    float acc = 0.f;
    for (int e = beg + lane; e < end; e += 16) acc += q[csr[e]];
    for (int off = 8; off > 0; off >>= 1) acc += __shfl_down(acc, off, 16);
    if (lane == 0) {
        float d = dis[node];
        float p = d * (acc + q[node]);
        qnext[node] = d * p;
        float add = c[k] * p;
        vacc[node] = first ? (c[0] + add) : (vacc[node] + add);
    }
}

// last gather step (k=6): no qnext write; fused block min/max partials
__global__ void gather_last(const int* __restrict__ rowptr, const int* __restrict__ csr,
                            const float* __restrict__ dis, const float* __restrict__ q,
                            const float* __restrict__ c,
                            float* __restrict__ vacc,
                            float* __restrict__ bmin, float* __restrict__ bmax, int n) {
    __shared__ float smn[TPB], smx[TPB];
    int t = threadIdx.x;
    int tid = blockIdx.x * blockDim.x + t;
    int node = tid >> 4;
    int lane = tid & 15;
    float v = 1e30f;
    bool act = (node < n);
    if (act) {
        int beg = rowptr[node], end = rowptr[node + 1];
        float acc = 0.f;
        for (int e = beg + lane; e < end; e += 16) acc += q[csr[e]];
        for (int off = 8; off > 0; off >>= 1) acc += __shfl_down(acc, off, 16);
        if (lane == 0) {
            float d = dis[node];
            float p = d * (acc + q[node]);
            v = vacc[node] + c[6] * p;
            vacc[node] = v;
        }
    }
    smn[t] = (act && lane == 0) ? v : 1e30f;
    smx[t] = (act && lane == 0) ? v : -1e30f;
    __syncthreads();
    for (int s = TPB / 2; s > 0; s >>= 1) {
        if (t < s) { smn[t] = fminf(smn[t], smn[t + s]); smx[t] = fmaxf(smx[t], smx[t + s]); }
        __syncthreads();
    }
    if (t == 0) { bmin[blockIdx.x] = smn[0]; bmax[blockIdx.x] = smx[0]; }
}

__global__ void minmax_final_kernel(const float* __restrict__ bmin, const float* __restrict__ bmax,
                                    int nblk, float* __restrict__ mnmx) {
    __shared__ float smn[TPB], smx[TPB];
    int t = threadIdx.x;
    float mn = 1e30f, mx = -1e30f;
    for (int i = t; i < nblk; i += TPB) {
        mn = fminf(mn, bmin[i]);
        mx = fmaxf(mx, bmax[i]);
    }
    smn[t] = mn; smx[t] = mx;
    __syncthreads();
    for (int s = TPB / 2; s > 0; s >>= 1) {
        if (t < s) { smn[t] = fminf(smn[t], smn[t + s]); smx[t] = fmaxf(smx[t], smx[t + s]); }
        __syncthreads();
    }
    if (t == 0) { mnmx[0] = smn[0]; mnmx[1] = smx[0]; }
}

__global__ void normalize_kernel(const float* __restrict__ v, const float* __restrict__ mnmx,
                                 float* __restrict__ out, int n) {
    int i = blockIdx.x * blockDim.x + threadIdx.x;
    if (i < n) {
        float mn = mnmx[0], mx = mnmx[1];
        out[i] = (v[i] - mn) / (mx - mn + 1e-15f);
    }
}

static inline int cdiv(long long a, int b) { return (int)((a + b - 1) / b); }

extern "C" void kernel_launch(void* const* d_in, const int* in_sizes, int n_in,
                              void* d_out, int out_size, void* d_ws, size_t ws_size,
                              hipStream_t stream) {
    const int N = out_size;               // 100000
    const int E = in_sizes[0] / 2;        // 3200000
    const int* src = (const int*)d_in[0];
    const int* dst = src + E;

    const float* W1 = (const float*)d_in[1];  const float* b1 = (const float*)d_in[2];
    const float* W2 = (const float*)d_in[3];  const float* b2 = (const float*)d_in[4];
    const float* W3 = (const float*)d_in[5];  const float* b3 = (const float*)d_in[6];
    const float* W4 = (const float*)d_in[7];  const float* b4 = (const float*)d_in[8];
    const float* W5 = (const float*)d_in[9];  const float* b5 = (const float*)d_in[10];
    const float* W6 = (const float*)d_in[11]; const float* b6 = (const float*)d_in[12];

    const int nb = (N + 255) >> 8;        // 391 buckets of 256 nodes
    const int gblocks = cdiv((long long)N * 16, TPB);   // 6250

    // workspace layout
    char* p = (char*)d_ws;
    int*   bucket_cnt    = (int*)p;   p += (size_t)512 * 4;
    int*   bucket_base   = (int*)p;   p += (size_t)512 * 4;
    int*   bucket_cursor = (int*)p;   p += (size_t)512 * 4;
    int*   rowptr        = (int*)p;   p += (size_t)(N + 1) * 4;
    int*   csr           = (int*)p;   p += (size_t)E * 4;
    unsigned int* binned = (unsigned int*)p; p += (size_t)E * 4;
    float* dis    = (float*)p; p += (size_t)N * 4;
    float* qA     = (float*)p; p += (size_t)N * 4;
    float* qB     = (float*)p; p += (size_t)N * 4;
    float* vacc   = (float*)p; p += (size_t)N * 4;
    float* c      = (float*)p; p += (size_t)8 * 4;
    float* bmin   = (float*)p; p += (size_t)gblocks * 4;
    float* bmax   = (float*)p; p += (size_t)gblocks * 4;
    float* mnmx   = (float*)p; p += 2 * 4;

    // ---- CSR build + coefficients (coef hidden in hist launch) ----
    hipMemsetAsync(bucket_cnt, 0, 512 * 4, stream);
    hist_coef_kernel<<<513, 256, 0, stream>>>(dst, E, bucket_cnt, nb,
                                              W1, b1, W2, b2, W3, b3,
                                              W4, b4, W5, b5, W6, b6, c);
    bucket_scan<<<1, 512, 0, stream>>>(bucket_cnt, nb, bucket_base, bucket_cursor,
                                       rowptr, N, E);
    binA_kernel<<<cdiv(E, BINE), 256, 0, stream>>>(src, dst, E, bucket_cursor, binned);
    csrB_kernel<<<nb, 256, 0, stream>>>(binned, bucket_base, N, rowptr, csr, dis);

    // ---- 6 scalar aggregations (k=6 fused with minmax partials) ----
    gather_step<<<gblocks, TPB, 0, stream>>>(rowptr, csr, dis, dis, c, 1, qA, vacc, N, 1);
    gather_step<<<gblocks, TPB, 0, stream>>>(rowptr, csr, dis, qA,  c, 2, qB, vacc, N, 0);
    gather_step<<<gblocks, TPB, 0, stream>>>(rowptr, csr, dis, qB,  c, 3, qA, vacc, N, 0);
    gather_step<<<gblocks, TPB, 0, stream>>>(rowptr, csr, dis, qA,  c, 4, qB, vacc, N, 0);
    gather_step<<<gblocks, TPB, 0, stream>>>(rowptr, csr, dis, qB,  c, 5, qA, vacc, N, 0);
    gather_last<<<gblocks, TPB, 0, stream>>>(rowptr, csr, dis, qA, c, vacc, bmin, bmax, N);

    // ---- min-max normalize ----
    minmax_final_kernel<<<1, TPB, 0, stream>>>(bmin, bmax, gblocks, mnmx);
    normalize_kernel<<<cdiv(N, TPB), TPB, 0, stream>>>(vacc, mnmx, (float*)d_out, N);
}

// Round 10
// 182.366 us; speedup vs baseline: 3.0961x; 1.1053x over previous
//
#include <hip/hip_runtime.h>
#include <hip/hip_cooperative_groups.h>

namespace cg = cooperative_groups;

// GCN 6-layer, N=100k, E=3.2M — Krylov form + binned CSR build.
// v = sum_{k=0..6} c_k * p_k, p_k = A_norm^k 1.
// Round 9: 1024-thread hist_coef (8-way i-split coef, kills the 44us pin);
// occupancy-gated cooperative fused gather (csr cached in registers, one
// launch for 6 steps + minmax + normalize), fallback to round-8 chain.

#define TPB 256
#define HTPB 1024        // hist_coef block size
#define NBPAD 400        // >= nb=391 buckets
#define BINE 8192        // edges per binA block
#define STAGE_CAP 12288  // per-bucket csr LDS stage (mean 8192, sigma ~90)
#define CB 512           // cooperative gather blocks (2 blocks/CU safe)
#define NSWEEP 13        // ceil(100000 / (CB*16)) node sweeps
#define IDXC 4           // cached csr entries per lane (deg <= 64 fast path)

// ---------- coefficient chain helper: 8-way i-split, 1024 threads ----------
template <int NK, int DIN>
__device__ void coef_step8(const float* __restrict__ W, const float* __restrict__ bias,
                           const float (*in)[128], float (*out)[128],
                           float (*part)[6][128], int tid) {
    int t = tid & 127, g = tid >> 7;          // 8 i-groups
    const int CH = (DIN + 7) / 8;
    int i0 = g * CH; if (i0 > DIN) i0 = DIN;
    int i1 = i0 + CH; if (i1 > DIN) i1 = DIN;
    float s[NK];
#pragma unroll
    for (int k = 0; k < NK; ++k) s[k] = 0.f;
    if (t < 125) {
#pragma unroll 4
        for (int i = i0; i < i1; ++i) {
            float w = W[i * 125 + t];
#pragma unroll
            for (int k = 0; k < NK; ++k) s[k] += w * in[k][i];
        }
    }
#pragma unroll
    for (int k = 0; k < NK; ++k) part[g][k][t] = s[k];
    __syncthreads();
    if (g == 0 && t < 125) {
#pragma unroll
        for (int k = 0; k < NK; ++k) {
            float acc = part[0][k][t];
#pragma unroll
            for (int gg = 1; gg < 8; ++gg) acc += part[gg][k][t];
            out[k + 1][t] = acc;
        }
        out[0][t] = bias[t];
    }
    __syncthreads();
}

// ---------- merged histogram + coefficient kernel (1024 threads) ----------
__global__ __launch_bounds__(HTPB) void hist_coef_kernel(
    const int* __restrict__ dst, int E, int* __restrict__ bucket_cnt, int nb,
    const float* __restrict__ W1, const float* __restrict__ b1,
    const float* __restrict__ W2, const float* __restrict__ b2,
    const float* __restrict__ W3, const float* __restrict__ b3,
    const float* __restrict__ W4, const float* __restrict__ b4,
    const float* __restrict__ W5, const float* __restrict__ b5,
    const float* __restrict__ W6, const float* __restrict__ b6,
    float* __restrict__ c) {
    __shared__ int h[NBPAD];
    __shared__ float A[6][128];
    __shared__ float B[6][128];
    __shared__ float part[8][6][128];
    int tid = threadIdx.x;
    int nbh = gridDim.x - 1;

    if ((int)blockIdx.x < nbh) {
        for (int j = tid; j < NBPAD; j += HTPB) h[j] = 0;
        __syncthreads();
        const int E4 = E >> 2;
        const int chunk4 = (E4 + nbh - 1) / nbh;
        const int b4 = (int)blockIdx.x * chunk4;
        const int e4 = (b4 + chunk4 < E4) ? (b4 + chunk4) : E4;
        const int4* d4 = (const int4*)dst;
        for (int j = b4 + tid; j < e4; j += HTPB) {
            int4 v = d4[j];
            atomicAdd(&h[v.x >> 8], 1);
            atomicAdd(&h[v.y >> 8], 1);
            atomicAdd(&h[v.z >> 8], 1);
            atomicAdd(&h[v.w >> 8], 1);
        }
        if (blockIdx.x == 0) {  // scalar tail (E % 4)
            for (int j = (E4 << 2) + tid; j < E; j += HTPB) atomicAdd(&h[dst[j] >> 8], 1);
        }
        __syncthreads();
        for (int j = tid; j < nb; j += HTPB)
            if (h[j]) atomicAdd(&bucket_cnt[j], h[j]);
        return;
    }

    // coefficient chain (8-way i-split)
    if (tid < 25) { A[1][tid] = W1[tid]; A[0][tid] = b1[tid]; }
    __syncthreads();
    coef_step8<2, 25>(W2, b2, A, B, part, tid);
    coef_step8<3, 125>(W3, b3, B, A, part, tid);
    coef_step8<4, 125>(W4, b4, A, B, part, tid);
    coef_step8<5, 125>(W5, b5, B, A, part, tid);
    // layer 6: c[k+1] = W6 . A[k]; waves 0..5 each handle one k
    int wave = tid >> 6, lane = tid & 63;
    if (wave < 6) {
        int k = wave;
        float acc = (lane < 125 ? W6[lane] * A[k][lane] : 0.f)
                  + (lane + 64 < 125 ? W6[lane + 64] * A[k][lane + 64] : 0.f);
        for (int off = 32; off > 0; off >>= 1) acc += __shfl_down(acc, off);
        if (lane == 0) c[k + 1] = acc;
    }
    if (tid == 0) c[0] = b6[0];
}

// exclusive scan of nb (<512) bucket counts; init base + cursor; rowptr[n]=E
__global__ void bucket_scan(const int* __restrict__ bucket_cnt, int nb,
                            int* __restrict__ bucket_base, int* __restrict__ bucket_cursor,
                            int* __restrict__ rowptr, int n, int E) {
    __shared__ int s[512];
    int t = threadIdx.x;
    int v = (t < nb) ? bucket_cnt[t] : 0;
    s[t] = v;
    __syncthreads();
    for (int off = 1; off < 512; off <<= 1) {
        int a = (t >= off) ? s[t - off] : 0;
        __syncthreads();
        s[t] += a;
        __syncthreads();
    }
    if (t < nb) {
        int ex = s[t] - v;
        bucket_base[t] = ex;
        bucket_cursor[t] = ex;
    }
    if (t == 0) { bucket_base[nb] = E; rowptr[n] = E; }
}

// ---------- binA: LDS-staged counting sort per 8192-edge block ----------
// binned word: (dst&255)<<24 | src   (src < 2^24)
__global__ __launch_bounds__(256) void binA_kernel(
    const int* __restrict__ src, const int* __restrict__ dst, int E,
    int* __restrict__ bucket_cursor, unsigned int* __restrict__ binned) {
    __shared__ int cnt[NBPAD];
    __shared__ int sa[512], sb[512];
    __shared__ int lbase[NBPAD];
    __shared__ int gbase[NBPAD];
    __shared__ int lcur[NBPAD];
    __shared__ unsigned int stagew[BINE];
    __shared__ unsigned short sbuck[BINE];
    int t = threadIdx.x;
    long long base = (long long)blockIdx.x * BINE;
    int ne = (E - base < BINE) ? (int)(E - base) : BINE;

    for (int j = t; j < NBPAD; j += 256) cnt[j] = 0;
    __syncthreads();

    // count phase: int4 loads, dst cached in registers
    int dv[8][4];
    const int4* d4 = (const int4*)(dst + base);
#pragma unroll
    for (int i = 0; i < 8; ++i) {
        int j4 = t + i * 256;
        if ((j4 << 2) + 3 < ne) {
            int4 v = d4[j4];
            dv[i][0] = v.x; dv[i][1] = v.y; dv[i][2] = v.z; dv[i][3] = v.w;
        } else {
#pragma unroll
            for (int cx = 0; cx < 4; ++cx) {
                int j = (j4 << 2) + cx;
                dv[i][cx] = (j < ne) ? dst[base + j] : -1;
            }
        }
#pragma unroll
        for (int cx = 0; cx < 4; ++cx)
            if (dv[i][cx] >= 0) atomicAdd(&cnt[dv[i][cx] >> 8], 1);
    }
    __syncthreads();
    // Kogge-Stone inclusive scan over 512 (ping-pong)
    for (int j = t; j < 512; j += 256) sa[j] = (j < NBPAD) ? cnt[j] : 0;
    __syncthreads();
    int* cu = sa; int* nx = sb;
    for (int off = 1; off < 512; off <<= 1) {
        for (int j = t; j < 512; j += 256) nx[j] = cu[j] + (j >= off ? cu[j - off] : 0);
        __syncthreads();
        int* tmp = cu; cu = nx; nx = tmp;
    }
    for (int j = t; j < NBPAD; j += 256) {
        int ex = cu[j] - cnt[j];
        lbase[j] = ex;
        lcur[j] = ex;
        gbase[j] = cnt[j] ? atomicAdd(&bucket_cursor[j], cnt[j]) : 0;
    }
    __syncthreads();
    // stage phase: int4 src loads, dst from registers
    const int4* s4 = (const int4*)(src + base);
#pragma unroll
    for (int i = 0; i < 8; ++i) {
        int j4 = t + i * 256;
        int sv[4];
        if ((j4 << 2) + 3 < ne) {
            int4 v = s4[j4];
            sv[0] = v.x; sv[1] = v.y; sv[2] = v.z; sv[3] = v.w;
        } else {
#pragma unroll
            for (int cx = 0; cx < 4; ++cx) {
                int j = (j4 << 2) + cx;
                sv[cx] = (j < ne) ? src[base + j] : -1;
            }
        }
#pragma unroll
        for (int cx = 0; cx < 4; ++cx) {
            if (dv[i][cx] >= 0) {
                int bk = dv[i][cx] >> 8;
                int pos = atomicAdd(&lcur[bk], 1);
                stagew[pos] = ((unsigned)(dv[i][cx] & 255) << 24) | (unsigned)sv[cx];
                sbuck[pos] = (unsigned short)bk;
            }
        }
    }
    __syncthreads();
    // coalesced chunk flush
    for (int j = t; j < ne; j += 256) {
        int bk = sbuck[j];
        binned[gbase[bk] + (j - lbase[bk])] = stagew[j];
    }
}

// ---------- csrB: one block per bucket -> rowptr, dis, node-sorted csr ----------
__global__ __launch_bounds__(256) void csrB_kernel(
    const unsigned int* __restrict__ binned,
    const int* __restrict__ bucket_base, int n,
    int* __restrict__ rowptr, int* __restrict__ csr, float* __restrict__ dis) {
    __shared__ int deg[256];
    __shared__ int ex[256];
    __shared__ int cur[256];
    __shared__ int stage[STAGE_CAP];
    int b = blockIdx.x;
    int t = threadIdx.x;
    int ebase = bucket_base[b], eend = bucket_base[b + 1];
    int esize = eend - ebase;
    int gnode = (b << 8) + t;
    deg[t] = 0;
    __syncthreads();
    for (int e = ebase + t; e < eend; e += 256)
        atomicAdd(&deg[binned[e] >> 24], 1);
    __syncthreads();
    int d = deg[t];
    ex[t] = d;
    __syncthreads();
    for (int off = 1; off < 256; off <<= 1) {
        int a = (t >= off) ? ex[t - off] : 0;
        __syncthreads();
        ex[t] += a;
        __syncthreads();
    }
    int excl = ex[t] - d;
    if (gnode < n) {
        rowptr[gnode] = ebase + excl;
        dis[gnode] = rsqrtf((float)d + 1.0f);   // +1 = self-loop
    }
    cur[t] = excl;
    __syncthreads();
    if (esize <= STAGE_CAP) {
        for (int e = ebase + t; e < eend; e += 256) {
            unsigned int pk = binned[e];
            int pos = atomicAdd(&cur[pk >> 24], 1);
            stage[pos] = (int)(pk & 0xffffffu);
        }
        __syncthreads();
        for (int e = t; e < esize; e += 256) csr[ebase + e] = stage[e];
    } else {  // statistical-impossibility fallback, keeps any input correct
        for (int e = ebase + t; e < eend; e += 256) {
            unsigned int pk = binned[e];
            int pos = atomicAdd(&cur[pk >> 24], 1);
            csr[ebase + pos] = (int)(pk & 0xffffffu);
        }
    }
}

// ---------- cooperative fused gather chain (occupancy-gated) ----------
// CB=512 blocks x 256 threads = 2 blocks/CU (8 waves/CU -> VGPR cap 256).
__global__ __launch_bounds__(256) void coop_gather(
    const int* __restrict__ rowptr, const int* __restrict__ csr,
    const float* __restrict__ dis, float* __restrict__ qA, float* __restrict__ qB,
    const float* __restrict__ c,
    float* __restrict__ bmin, float* __restrict__ bmax,
    float* __restrict__ out, int n) {
    cg::grid_group grid = cg::this_grid();
    __shared__ float smn[256], smx[256];
    int t = threadIdx.x;
    int lane = t & 15, grp = t >> 4;
    int gid0 = (int)blockIdx.x * 16 + grp;       // node id at sweep 0, stride CB*16

    int beg[NSWEEP], end[NSWEEP];
    int idx[NSWEEP][IDXC];
    float dd[NSWEEP], qown[NSWEEP], vacc[NSWEEP];
    float cc[7];
#pragma unroll
    for (int k = 0; k < 7; ++k) cc[k] = c[k];

    // prefetch graph into registers (csr read ONCE for deg<=64)
#pragma unroll
    for (int s = 0; s < NSWEEP; ++s) {
        int node = gid0 + s * (CB * 16);
        bool act = node < n;
        beg[s] = act ? rowptr[node] : 0;
        end[s] = act ? rowptr[node + 1] : 0;
        dd[s]  = act ? dis[node] : 0.f;
        qown[s] = dd[s];                 // q0 = dis .* ones
        vacc[s] = cc[0];
#pragma unroll
        for (int j = 0; j < IDXC; ++j) {
            int e = beg[s] + lane + j * 16;
            idx[s][j] = (e < end[s]) ? csr[e] : -1;
        }
    }

    const float* q = dis;
    for (int k = 1; k <= 6; ++k) {
        float* qn = (k & 1) ? qA : qB;
#pragma unroll
        for (int s = 0; s < NSWEEP; ++s) {
            float acc = 0.f;
#pragma unroll
            for (int j = 0; j < IDXC; ++j)
                if (idx[s][j] >= 0) acc += q[idx[s][j]];
            for (int e = beg[s] + IDXC * 16 + lane; e < end[s]; e += 16)
                acc += q[csr[e]];        // deg > 64 tail (statistically ~never)
#pragma unroll
            for (int off = 8; off > 0; off >>= 1) acc += __shfl_down(acc, off, 16);
            int node = gid0 + s * (CB * 16);
            if (lane == 0 && node < n) {
                float p = dd[s] * (acc + qown[s]);
                qown[s] = dd[s] * p;
                if (k < 6) qn[node] = qown[s];
                vacc[s] += cc[k] * p;
            }
        }
        if (k < 6) {
            __threadfence();
            grid.sync();
            q = qn;
        }
    }

    // block-local min/max of vacc (lane0s hold real values)
    float mn = 1e30f, mx = -1e30f;
    if (lane == 0) {
#pragma unroll
        for (int s = 0; s < NSWEEP; ++s) {
            int node = gid0 + s * (CB * 16);
            if (node < n) { mn = fminf(mn, vacc[s]); mx = fmaxf(mx, vacc[s]); }
        }
    }
    smn[t] = mn; smx[t] = mx;
    __syncthreads();
    for (int sft = 128; sft > 0; sft >>= 1) {
        if (t < sft) {
            smn[t] = fminf(smn[t], smn[t + sft]);
            smx[t] = fmaxf(smx[t], smx[t + sft]);
        }
        __syncthreads();
    }
    if (t == 0) { bmin[blockIdx.x] = smn[0]; bmax[blockIdx.x] = smx[0]; }
    __threadfence();
    grid.sync();

    // redundant per-block final reduce + normalize
    mn = 1e30f; mx = -1e30f;
    for (int j = t; j < CB; j += 256) {
        mn = fminf(mn, bmin[j]);
        mx = fmaxf(mx, bmax[j]);
    }
    smn[t] = mn; smx[t] = mx;
    __syncthreads();
    for (int sft = 128; sft > 0; sft >>= 1) {
        if (t < sft) {
            smn[t] = fminf(smn[t], smn[t + sft]);
            smx[t] = fmaxf(smx[t], smx[t + sft]);
        }
        __syncthreads();
    }
    mn = smn[0]; mx = smx[0];
    float inv = 1.0f / (mx - mn + 1e-15f);
    if (lane == 0) {
#pragma unroll
        for (int s = 0; s < NSWEEP; ++s) {
            int node = gid0 + s * (CB * 16);
            if (node < n) out[node] = (vacc[s] - mn) * inv;
        }
    }
}

// ---------- fallback chain (round-8, known-good) ----------
__global__ void gather_step(const int* __restrict__ rowptr, const int* __restrict__ csr,
                            const float* __restrict__ dis, const float* __restrict__ q,
                            const float* __restrict__ c, int k,
                            float* __restrict__ qnext, float* __restrict__ vacc,
                            int n, int first) {
    int tid = blockIdx.x * blockDim.x + threadIdx.x;
    int node = tid >> 4;
    int lane = tid & 15;
    if (node >= n) return;
    int beg = rowptr[node], end = rowptr[node + 1];
    float acc = 0.f;
    for (int e = beg + lane; e < end; e += 16) acc += q[csr[e]];
    for (int off = 8; off > 0; off >>= 1) acc += __shfl_down(acc, off, 16);
    if (lane == 0) {
        float d = dis[node];
        float p = d * (acc + q[node]);
        qnext[node] = d * p;
        float add = c[k] * p;
        vacc[node] = first ? (c[0] + add) : (vacc[node] + add);
    }
}

__global__ void gather_last(const int* __restrict__ rowptr, const int* __restrict__ csr,
                            const float* __restrict__ dis, const float* __restrict__ q,
                            const float* __restrict__ c,
                            float* __restrict__ vacc,
                            float* __restrict__ bmin, float* __restrict__ bmax, int n) {
    __shared__ float smn[TPB], smx[TPB];
    int t = threadIdx.x;
    int tid = blockIdx.x * blockDim.x + t;
    int node = tid >> 4;
    int lane = tid & 15;
    float v = 1e30f;
    bool act = (node < n);
    if (act) {
        int beg = rowptr[node], end = rowptr[node + 1];
        float acc = 0.f;
        for (int e = beg + lane; e < end; e += 16) acc += q[csr[e]];
        for (int off = 8; off > 0; off >>= 1) acc += __shfl_down(acc, off, 16);
        if (lane == 0) {
            float d = dis[node];
            float p = d * (acc + q[node]);
            v = vacc[node] + c[6] * p;
            vacc[node] = v;
        }
    }
    smn[t] = (act && lane == 0) ? v : 1e30f;
    smx[t] = (act && lane == 0) ? v : -1e30f;
    __syncthreads();
    for (int s = TPB / 2; s > 0; s >>= 1) {
        if (t < s) { smn[t] = fminf(smn[t], smn[t + s]); smx[t] = fmaxf(smx[t], smx[t + s]); }
        __syncthreads();
    }
    if (t == 0) { bmin[blockIdx.x] = smn[0]; bmax[blockIdx.x] = smx[0]; }
}

__global__ void minmax_final_kernel(const float* __restrict__ bmin, const float* __restrict__ bmax,
                                    int nblk, float* __restrict__ mnmx) {
    __shared__ float smn[TPB], smx[TPB];
    int t = threadIdx.x;
    float mn = 1e30f, mx = -1e30f;
    for (int i = t; i < nblk; i += TPB) {
        mn = fminf(mn, bmin[i]);
        mx = fmaxf(mx, bmax[i]);
    }
    smn[t] = mn; smx[t] = mx;
    __syncthreads();
    for (int s = TPB / 2; s > 0; s >>= 1) {
        if (t < s) { smn[t] = fminf(smn[t], smn[t + s]); smx[t] = fmaxf(smx[t], smx[t + s]); }
        __syncthreads();
    }
    if (t == 0) { mnmx[0] = smn[0]; mnmx[1] = smx[0]; }
}

__global__ void normalize_kernel(const float* __restrict__ v, const float* __restrict__ mnmx,
                                 float* __restrict__ out, int n) {
    int i = blockIdx.x * blockDim.x + threadIdx.x;
    if (i < n) {
        float mn = mnmx[0], mx = mnmx[1];
        out[i] = (v[i] - mn) / (mx - mn + 1e-15f);
    }
}

static inline int cdiv(long long a, int b) { return (int)((a + b - 1) / b); }

extern "C" void kernel_launch(void* const* d_in, const int* in_sizes, int n_in,
                              void* d_out, int out_size, void* d_ws, size_t ws_size,
                              hipStream_t stream) {
    const int N = out_size;               // 100000
    const int E = in_sizes[0] / 2;        // 3200000
    const int* src = (const int*)d_in[0];
    const int* dst = src + E;

    const float* W1 = (const float*)d_in[1];  const float* b1 = (const float*)d_in[2];
    const float* W2 = (const float*)d_in[3];  const float* b2 = (const float*)d_in[4];
    const float* W3 = (const float*)d_in[5];  const float* b3 = (const float*)d_in[6];
    const float* W4 = (const float*)d_in[7];  const float* b4 = (const float*)d_in[8];
    const float* W5 = (const float*)d_in[9];  const float* b5 = (const float*)d_in[10];
    const float* W6 = (const float*)d_in[11]; const float* b6 = (const float*)d_in[12];

    const int nb = (N + 255) >> 8;        // 391 buckets of 256 nodes
    const int gblocks = cdiv((long long)N * 16, TPB);   // 6250

    // workspace layout
    char* p = (char*)d_ws;
    int*   bucket_cnt    = (int*)p;   p += (size_t)512 * 4;
    int*   bucket_base   = (int*)p;   p += (size_t)512 * 4;
    int*   bucket_cursor = (int*)p;   p += (size_t)512 * 4;
    int*   rowptr        = (int*)p;   p += (size_t)(N + 1) * 4;
    int*   csr           = (int*)p;   p += (size_t)E * 4;
    unsigned int* binned = (unsigned int*)p; p += (size_t)E * 4;
    float* dis    = (float*)p; p += (size_t)N * 4;
    float* qA     = (float*)p; p += (size_t)N * 4;
    float* qB     = (float*)p; p += (size_t)N * 4;
    float* vacc   = (float*)p; p += (size_t)N * 4;
    float* c      = (float*)p; p += (size_t)8 * 4;
    float* bmin   = (float*)p; p += (size_t)gblocks * 4;
    float* bmax   = (float*)p; p += (size_t)gblocks * 4;
    float* mnmx   = (float*)p; p += 2 * 4;

    // ---- CSR build + coefficients (coef hidden in hist launch) ----
    hipMemsetAsync(bucket_cnt, 0, 512 * 4, stream);
    const int nbh = 128;                  // 1024-thread hist blocks
    hist_coef_kernel<<<nbh + 1, HTPB, 0, stream>>>(dst, E, bucket_cnt, nb,
                                                   W1, b1, W2, b2, W3, b3,
                                                   W4, b4, W5, b5, W6, b6, c);
    bucket_scan<<<1, 512, 0, stream>>>(bucket_cnt, nb, bucket_base, bucket_cursor,
                                       rowptr, N, E);
    binA_kernel<<<cdiv(E, BINE), 256, 0, stream>>>(src, dst, E, bucket_cursor, binned);
    csrB_kernel<<<nb, 256, 0, stream>>>(binned, bucket_base, N, rowptr, csr, dis);

    // ---- gather chain: cooperative if occupancy-feasible, else fallback ----
    int occ = 0;
    hipError_t oerr = hipOccupancyMaxActiveBlocksPerMultiprocessor(
        &occ, (const void*)coop_gather, 256, 0);
    bool canCoop = (oerr == hipSuccess) && ((long long)occ * 256 >= CB) &&
                   (N <= CB * 16 * NSWEEP);
    if (canCoop) {
        const int* rp = rowptr; const int* cs = csr;
        const float* dis_c = dis; const float* cc = c;
        float* qA_ = qA; float* qB_ = qB;
        float* bmin_ = bmin; float* bmax_ = bmax;
        float* outp = (float*)d_out;
        int n_ = N;
        void* args[] = { &rp, &cs, &dis_c, &qA_, &qB_, &cc, &bmin_, &bmax_, &outp, &n_ };
        hipLaunchCooperativeKernel((const void*)coop_gather, dim3(CB), dim3(256),
                                   args, 0, stream);
    } else {
        gather_step<<<gblocks, TPB, 0, stream>>>(rowptr, csr, dis, dis, c, 1, qA, vacc, N, 1);
        gather_step<<<gblocks, TPB, 0, stream>>>(rowptr, csr, dis, qA,  c, 2, qB, vacc, N, 0);
        gather_step<<<gblocks, TPB, 0, stream>>>(rowptr, csr, dis, qB,  c, 3, qA, vacc, N, 0);
        gather_step<<<gblocks, TPB, 0, stream>>>(rowptr, csr, dis, qA,  c, 4, qB, vacc, N, 0);
        gather_step<<<gblocks, TPB, 0, stream>>>(rowptr, csr, dis, qB,  c, 5, qA, vacc, N, 0);
        gather_last<<<gblocks, TPB, 0, stream>>>(rowptr, csr, dis, qA, c, vacc, bmin, bmax, N);
        minmax_final_kernel<<<1, TPB, 0, stream>>>(bmin, bmax, gblocks, mnmx);
        normalize_kernel<<<cdiv(N, TPB), TPB, 0, stream>>>(vacc, mnmx, (float*)d_out, N);
    }
}

// Round 11
// 181.672 us; speedup vs baseline: 3.1079x; 1.0038x over previous
//
#include <hip/hip_runtime.h>
#include <hip/hip_cooperative_groups.h>

namespace cg = cooperative_groups;

// GCN 6-layer, N=100k, E=3.2M — Krylov form + binned CSR build.
// v = sum_{k=0..6} c_k * p_k, p_k = A_norm^k 1.
// Round 10: coop gather re-geometried to CB=1024 x NSWEEP=7 (4 blocks/CU,
// double the latency hiding; R9's CB=512 was occupancy-starved, +12us vs
// chain). Occupancy-gated; otherwise plain launch chain (no 512 variant).

#define TPB 256
#define HTPB 1024        // hist_coef block size
#define NBPAD 400        // >= nb=391 buckets
#define BINE 8192        // edges per binA block
#define STAGE_CAP 12288  // per-bucket csr LDS stage (mean 8192, sigma ~90)
#define IDXC 4           // cached csr entries per lane (deg <= 64 fast path)

// ---------- coefficient chain helper: 8-way i-split, 1024 threads ----------
template <int NK, int DIN>
__device__ void coef_step8(const float* __restrict__ W, const float* __restrict__ bias,
                           const float (*in)[128], float (*out)[128],
                           float (*part)[6][128], int tid) {
    int t = tid & 127, g = tid >> 7;          // 8 i-groups
    const int CH = (DIN + 7) / 8;
    int i0 = g * CH; if (i0 > DIN) i0 = DIN;
    int i1 = i0 + CH; if (i1 > DIN) i1 = DIN;
    float s[NK];
#pragma unroll
    for (int k = 0; k < NK; ++k) s[k] = 0.f;
    if (t < 125) {
#pragma unroll 4
        for (int i = i0; i < i1; ++i) {
            float w = W[i * 125 + t];
#pragma unroll
            for (int k = 0; k < NK; ++k) s[k] += w * in[k][i];
        }
    }
#pragma unroll
    for (int k = 0; k < NK; ++k) part[g][k][t] = s[k];
    __syncthreads();
    if (g == 0 && t < 125) {
#pragma unroll
        for (int k = 0; k < NK; ++k) {
            float acc = part[0][k][t];
#pragma unroll
            for (int gg = 1; gg < 8; ++gg) acc += part[gg][k][t];
            out[k + 1][t] = acc;
        }
        out[0][t] = bias[t];
    }
    __syncthreads();
}

// ---------- merged histogram + coefficient kernel (1024 threads) ----------
__global__ __launch_bounds__(HTPB) void hist_coef_kernel(
    const int* __restrict__ dst, int E, int* __restrict__ bucket_cnt, int nb,
    const float* __restrict__ W1, const float* __restrict__ b1,
    const float* __restrict__ W2, const float* __restrict__ b2,
    const float* __restrict__ W3, const float* __restrict__ b3,
    const float* __restrict__ W4, const float* __restrict__ b4,
    const float* __restrict__ W5, const float* __restrict__ b5,
    const float* __restrict__ W6, const float* __restrict__ b6,
    float* __restrict__ c) {
    __shared__ int h[NBPAD];
    __shared__ float A[6][128];
    __shared__ float B[6][128];
    __shared__ float part[8][6][128];
    int tid = threadIdx.x;
    int nbh = gridDim.x - 1;

    if ((int)blockIdx.x < nbh) {
        for (int j = tid; j < NBPAD; j += HTPB) h[j] = 0;
        __syncthreads();
        const int E4 = E >> 2;
        const int chunk4 = (E4 + nbh - 1) / nbh;
        const int b4 = (int)blockIdx.x * chunk4;
        const int e4 = (b4 + chunk4 < E4) ? (b4 + chunk4) : E4;
        const int4* d4 = (const int4*)dst;
        for (int j = b4 + tid; j < e4; j += HTPB) {
            int4 v = d4[j];
            atomicAdd(&h[v.x >> 8], 1);
            atomicAdd(&h[v.y >> 8], 1);
            atomicAdd(&h[v.z >> 8], 1);
            atomicAdd(&h[v.w >> 8], 1);
        }
        if (blockIdx.x == 0) {  // scalar tail (E % 4)
            for (int j = (E4 << 2) + tid; j < E; j += HTPB) atomicAdd(&h[dst[j] >> 8], 1);
        }
        __syncthreads();
        for (int j = tid; j < nb; j += HTPB)
            if (h[j]) atomicAdd(&bucket_cnt[j], h[j]);
        return;
    }

    // coefficient chain (8-way i-split)
    if (tid < 25) { A[1][tid] = W1[tid]; A[0][tid] = b1[tid]; }
    __syncthreads();
    coef_step8<2, 25>(W2, b2, A, B, part, tid);
    coef_step8<3, 125>(W3, b3, B, A, part, tid);
    coef_step8<4, 125>(W4, b4, A, B, part, tid);
    coef_step8<5, 125>(W5, b5, B, A, part, tid);
    // layer 6: c[k+1] = W6 . A[k]; waves 0..5 each handle one k
    int wave = tid >> 6, lane = tid & 63;
    if (wave < 6) {
        int k = wave;
        float acc = (lane < 125 ? W6[lane] * A[k][lane] : 0.f)
                  + (lane + 64 < 125 ? W6[lane + 64] * A[k][lane + 64] : 0.f);
        for (int off = 32; off > 0; off >>= 1) acc += __shfl_down(acc, off);
        if (lane == 0) c[k + 1] = acc;
    }
    if (tid == 0) c[0] = b6[0];
}

// exclusive scan of nb (<512) bucket counts; init base + cursor; rowptr[n]=E
__global__ void bucket_scan(const int* __restrict__ bucket_cnt, int nb,
                            int* __restrict__ bucket_base, int* __restrict__ bucket_cursor,
                            int* __restrict__ rowptr, int n, int E) {
    __shared__ int s[512];
    int t = threadIdx.x;
    int v = (t < nb) ? bucket_cnt[t] : 0;
    s[t] = v;
    __syncthreads();
    for (int off = 1; off < 512; off <<= 1) {
        int a = (t >= off) ? s[t - off] : 0;
        __syncthreads();
        s[t] += a;
        __syncthreads();
    }
    if (t < nb) {
        int ex = s[t] - v;
        bucket_base[t] = ex;
        bucket_cursor[t] = ex;
    }
    if (t == 0) { bucket_base[nb] = E; rowptr[n] = E; }
}

// ---------- binA: LDS-staged counting sort per 8192-edge block ----------
// binned word: (dst&255)<<24 | src   (src < 2^24)
__global__ __launch_bounds__(256) void binA_kernel(
    const int* __restrict__ src, const int* __restrict__ dst, int E,
    int* __restrict__ bucket_cursor, unsigned int* __restrict__ binned) {
    __shared__ int cnt[NBPAD];
    __shared__ int sa[512], sb[512];
    __shared__ int lbase[NBPAD];
    __shared__ int gbase[NBPAD];
    __shared__ int lcur[NBPAD];
    __shared__ unsigned int stagew[BINE];
    __shared__ unsigned short sbuck[BINE];
    int t = threadIdx.x;
    long long base = (long long)blockIdx.x * BINE;
    int ne = (E - base < BINE) ? (int)(E - base) : BINE;

    for (int j = t; j < NBPAD; j += 256) cnt[j] = 0;
    __syncthreads();

    // count phase: int4 loads, dst cached in registers
    int dv[8][4];
    const int4* d4 = (const int4*)(dst + base);
#pragma unroll
    for (int i = 0; i < 8; ++i) {
        int j4 = t + i * 256;
        if ((j4 << 2) + 3 < ne) {
            int4 v = d4[j4];
            dv[i][0] = v.x; dv[i][1] = v.y; dv[i][2] = v.z; dv[i][3] = v.w;
        } else {
#pragma unroll
            for (int cx = 0; cx < 4; ++cx) {
                int j = (j4 << 2) + cx;
                dv[i][cx] = (j < ne) ? dst[base + j] : -1;
            }
        }
#pragma unroll
        for (int cx = 0; cx < 4; ++cx)
            if (dv[i][cx] >= 0) atomicAdd(&cnt[dv[i][cx] >> 8], 1);
    }
    __syncthreads();
    // Kogge-Stone inclusive scan over 512 (ping-pong)
    for (int j = t; j < 512; j += 256) sa[j] = (j < NBPAD) ? cnt[j] : 0;
    __syncthreads();
    int* cu = sa; int* nx = sb;
    for (int off = 1; off < 512; off <<= 1) {
        for (int j = t; j < 512; j += 256) nx[j] = cu[j] + (j >= off ? cu[j - off] : 0);
        __syncthreads();
        int* tmp = cu; cu = nx; nx = tmp;
    }
    for (int j = t; j < NBPAD; j += 256) {
        int ex = cu[j] - cnt[j];
        lbase[j] = ex;
        lcur[j] = ex;
        gbase[j] = cnt[j] ? atomicAdd(&bucket_cursor[j], cnt[j]) : 0;
    }
    __syncthreads();
    // stage phase: int4 src loads, dst from registers
    const int4* s4 = (const int4*)(src + base);
#pragma unroll
    for (int i = 0; i < 8; ++i) {
        int j4 = t + i * 256;
        int sv[4];
        if ((j4 << 2) + 3 < ne) {
            int4 v = s4[j4];
            sv[0] = v.x; sv[1] = v.y; sv[2] = v.z; sv[3] = v.w;
        } else {
#pragma unroll
            for (int cx = 0; cx < 4; ++cx) {
                int j = (j4 << 2) + cx;
                sv[cx] = (j < ne) ? src[base + j] : -1;
            }
        }
#pragma unroll
        for (int cx = 0; cx < 4; ++cx) {
            if (dv[i][cx] >= 0) {
                int bk = dv[i][cx] >> 8;
                int pos = atomicAdd(&lcur[bk], 1);
                stagew[pos] = ((unsigned)(dv[i][cx] & 255) << 24) | (unsigned)sv[cx];
                sbuck[pos] = (unsigned short)bk;
            }
        }
    }
    __syncthreads();
    // coalesced chunk flush
    for (int j = t; j < ne; j += 256) {
        int bk = sbuck[j];
        binned[gbase[bk] + (j - lbase[bk])] = stagew[j];
    }
}

// ---------- csrB: one block per bucket -> rowptr, dis, node-sorted csr ----------
__global__ __launch_bounds__(256) void csrB_kernel(
    const unsigned int* __restrict__ binned,
    const int* __restrict__ bucket_base, int n,
    int* __restrict__ rowptr, int* __restrict__ csr, float* __restrict__ dis) {
    __shared__ int deg[256];
    __shared__ int ex[256];
    __shared__ int cur[256];
    __shared__ int stage[STAGE_CAP];
    int b = blockIdx.x;
    int t = threadIdx.x;
    int ebase = bucket_base[b], eend = bucket_base[b + 1];
    int esize = eend - ebase;
    int gnode = (b << 8) + t;
    deg[t] = 0;
    __syncthreads();
    for (int e = ebase + t; e < eend; e += 256)
        atomicAdd(&deg[binned[e] >> 24], 1);
    __syncthreads();
    int d = deg[t];
    ex[t] = d;
    __syncthreads();
    for (int off = 1; off < 256; off <<= 1) {
        int a = (t >= off) ? ex[t - off] : 0;
        __syncthreads();
        ex[t] += a;
        __syncthreads();
    }
    int excl = ex[t] - d;
    if (gnode < n) {
        rowptr[gnode] = ebase + excl;
        dis[gnode] = rsqrtf((float)d + 1.0f);   // +1 = self-loop
    }
    cur[t] = excl;
    __syncthreads();
    if (esize <= STAGE_CAP) {
        for (int e = ebase + t; e < eend; e += 256) {
            unsigned int pk = binned[e];
            int pos = atomicAdd(&cur[pk >> 24], 1);
            stage[pos] = (int)(pk & 0xffffffu);
        }
        __syncthreads();
        for (int e = t; e < esize; e += 256) csr[ebase + e] = stage[e];
    } else {  // statistical-impossibility fallback, keeps any input correct
        for (int e = ebase + t; e < eend; e += 256) {
            unsigned int pk = binned[e];
            int pos = atomicAdd(&cur[pk >> 24], 1);
            csr[ebase + pos] = (int)(pk & 0xffffffu);
        }
    }
}

// ---------- cooperative fused gather chain (templated geometry) ----------
// NS sweeps, CBT blocks x 256 threads. Launched only if occupancy check
// guarantees CBT co-resident blocks.
template <int NS, int CBT>
__global__ __launch_bounds__(256) void coop_gather_t(
    const int* __restrict__ rowptr, const int* __restrict__ csr,
    const float* __restrict__ dis, float* __restrict__ qA, float* __restrict__ qB,
    const float* __restrict__ c,
    float* __restrict__ bmin, float* __restrict__ bmax,
    float* __restrict__ out, int n) {
    cg::grid_group grid = cg::this_grid();
    __shared__ float smn[256], smx[256];
    int t = threadIdx.x;
    int lane = t & 15, grp = t >> 4;
    int gid0 = (int)blockIdx.x * 16 + grp;       // node id at sweep 0, stride CBT*16

    int beg[NS], end[NS];
    int idx[NS][IDXC];
    float dd[NS], qown[NS], vacc[NS];
    float cc[7];
#pragma unroll
    for (int k = 0; k < 7; ++k) cc[k] = c[k];

    // prefetch graph into registers (csr read ONCE for deg<=64)
#pragma unroll
    for (int s = 0; s < NS; ++s) {
        int node = gid0 + s * (CBT * 16);
        bool act = node < n;
        beg[s] = act ? rowptr[node] : 0;
        end[s] = act ? rowptr[node + 1] : 0;
        dd[s]  = act ? dis[node] : 0.f;
        qown[s] = dd[s];                 // q0 = dis .* ones
        vacc[s] = cc[0];
#pragma unroll
        for (int j = 0; j < IDXC; ++j) {
            int e = beg[s] + lane + j * 16;
            idx[s][j] = (e < end[s]) ? csr[e] : -1;
        }
    }

    const float* q = dis;
    for (int k = 1; k <= 6; ++k) {
        float* qn = (k & 1) ? qA : qB;
#pragma unroll
        for (int s = 0; s < NS; ++s) {
            float acc = 0.f;
#pragma unroll
            for (int j = 0; j < IDXC; ++j)
                if (idx[s][j] >= 0) acc += q[idx[s][j]];
            for (int e = beg[s] + IDXC * 16 + lane; e < end[s]; e += 16)
                acc += q[csr[e]];        // deg > 64 tail (statistically ~never)
#pragma unroll
            for (int off = 8; off > 0; off >>= 1) acc += __shfl_down(acc, off, 16);
            int node = gid0 + s * (CBT * 16);
            if (lane == 0 && node < n) {
                float p = dd[s] * (acc + qown[s]);
                qown[s] = dd[s] * p;
                if (k < 6) qn[node] = qown[s];
                vacc[s] += cc[k] * p;
            }
        }
        if (k < 6) {
            __threadfence();
            grid.sync();
            q = qn;
        }
    }

    // block-local min/max of vacc (lane0s hold real values)
    float mn = 1e30f, mx = -1e30f;
    if (lane == 0) {
#pragma unroll
        for (int s = 0; s < NS; ++s) {
            int node = gid0 + s * (CBT * 16);
            if (node < n) { mn = fminf(mn, vacc[s]); mx = fmaxf(mx, vacc[s]); }
        }
    }
    smn[t] = mn; smx[t] = mx;
    __syncthreads();
    for (int sft = 128; sft > 0; sft >>= 1) {
        if (t < sft) {
            smn[t] = fminf(smn[t], smn[t + sft]);
            smx[t] = fmaxf(smx[t], smx[t + sft]);
        }
        __syncthreads();
    }
    if (t == 0) { bmin[blockIdx.x] = smn[0]; bmax[blockIdx.x] = smx[0]; }
    __threadfence();
    grid.sync();

    // redundant per-block final reduce + normalize
    mn = 1e30f; mx = -1e30f;
    for (int j = t; j < CBT; j += 256) {
        mn = fminf(mn, bmin[j]);
        mx = fmaxf(mx, bmax[j]);
    }
    smn[t] = mn; smx[t] = mx;
    __syncthreads();
    for (int sft = 128; sft > 0; sft >>= 1) {
        if (t < sft) {
            smn[t] = fminf(smn[t], smn[t + sft]);
            smx[t] = fmaxf(smx[t], smx[t + sft]);
        }
        __syncthreads();
    }
    mn = smn[0]; mx = smx[0];
    float inv = 1.0f / (mx - mn + 1e-15f);
    if (lane == 0) {
#pragma unroll
        for (int s = 0; s < NS; ++s) {
            int node = gid0 + s * (CBT * 16);
            if (node < n) out[node] = (vacc[s] - mn) * inv;
        }
    }
}

// ---------- fallback chain (round-8, known-good) ----------
__global__ void gather_step(const int* __restrict__ rowptr, const int* __restrict__ csr,
                            const float* __restrict__ dis, const float* __restrict__ q,
                            const float* __restrict__ c, int k,
                            float* __restrict__ qnext, float* __restrict__ vacc,
                            int n, int first) {
    int tid = blockIdx.x * blockDim.x + threadIdx.x;
    int node = tid >> 4;
    int lane = tid & 15;
    if (node >= n) return;
    int beg = rowptr[node], end = rowptr[node + 1];
    float acc = 0.f;
    for (int e = beg + lane; e < end; e += 16) acc += q[csr[e]];
    for (int off = 8; off > 0; off >>= 1) acc += __shfl_down(acc, off, 16);
    if (lane == 0) {
        float d = dis[node];
        float p = d * (acc + q[node]);
        qnext[node] = d * p;
        float add = c[k] * p;
        vacc[node] = first ? (c[0] + add) : (vacc[node] + add);
    }
}

__global__ void gather_last(const int* __restrict__ rowptr, const int* __restrict__ csr,
                            const float* __restrict__ dis, const float* __restrict__ q,
                            const float* __restrict__ c,
                            float* __restrict__ vacc,
                            float* __restrict__ bmin, float* __restrict__ bmax, int n) {
    __shared__ float smn[TPB], smx[TPB];
    int t = threadIdx.x;
    int tid = blockIdx.x * blockDim.x + t;
    int node = tid >> 4;
    int lane = tid & 15;
    float v = 1e30f;
    bool act = (node < n);
    if (act) {
        int beg = rowptr[node], end = rowptr[node + 1];
        float acc = 0.f;
        for (int e = beg + lane; e < end; e += 16) acc += q[csr[e]];
        for (int off = 8; off > 0; off >>= 1) acc += __shfl_down(acc, off, 16);
        if (lane == 0) {
            float d = dis[node];
            float p = d * (acc + q[node]);
            v = vacc[node] + c[6] * p;
            vacc[node] = v;
        }
    }
    smn[t] = (act && lane == 0) ? v : 1e30f;
    smx[t] = (act && lane == 0) ? v : -1e30f;
    __syncthreads();
    for (int s = TPB / 2; s > 0; s >>= 1) {
        if (t < s) { smn[t] = fminf(smn[t], smn[t + s]); smx[t] = fmaxf(smx[t], smx[t + s]); }
        __syncthreads();
    }
    if (t == 0) { bmin[blockIdx.x] = smn[0]; bmax[blockIdx.x] = smx[0]; }
}

__global__ void minmax_final_kernel(const float* __restrict__ bmin, const float* __restrict__ bmax,
                                    int nblk, float* __restrict__ mnmx) {
    __shared__ float smn[TPB], smx[TPB];
    int t = threadIdx.x;
    float mn = 1e30f, mx = -1e30f;
    for (int i = t; i < nblk; i += TPB) {
        mn = fminf(mn, bmin[i]);
        mx = fmaxf(mx, bmax[i]);
    }
    smn[t] = mn; smx[t] = mx;
    __syncthreads();
    for (int s = TPB / 2; s > 0; s >>= 1) {
        if (t < s) { smn[t] = fminf(smn[t], smn[t + s]); smx[t] = fmaxf(smx[t], smx[t + s]); }
        __syncthreads();
    }
    if (t == 0) { mnmx[0] = smn[0]; mnmx[1] = smx[0]; }
}

__global__ void normalize_kernel(const float* __restrict__ v, const float* __restrict__ mnmx,
                                 float* __restrict__ out, int n) {
    int i = blockIdx.x * blockDim.x + threadIdx.x;
    if (i < n) {
        float mn = mnmx[0], mx = mnmx[1];
        out[i] = (v[i] - mn) / (mx - mn + 1e-15f);
    }
}

static inline int cdiv(long long a, int b) { return (int)((a + b - 1) / b); }

extern "C" void kernel_launch(void* const* d_in, const int* in_sizes, int n_in,
                              void* d_out, int out_size, void* d_ws, size_t ws_size,
                              hipStream_t stream) {
    const int N = out_size;               // 100000
    const int E = in_sizes[0] / 2;        // 3200000
    const int* src = (const int*)d_in[0];
    const int* dst = src + E;

    const float* W1 = (const float*)d_in[1];  const float* b1 = (const float*)d_in[2];
    const float* W2 = (const float*)d_in[3];  const float* b2 = (const float*)d_in[4];
    const float* W3 = (const float*)d_in[5];  const float* b3 = (const float*)d_in[6];
    const float* W4 = (const float*)d_in[7];  const float* b4 = (const float*)d_in[8];
    const float* W5 = (const float*)d_in[9];  const float* b5 = (const float*)d_in[10];
    const float* W6 = (const float*)d_in[11]; const float* b6 = (const float*)d_in[12];

    const int nb = (N + 255) >> 8;        // 391 buckets of 256 nodes
    const int gblocks = cdiv((long long)N * 16, TPB);   // 6250

    // workspace layout
    char* p = (char*)d_ws;
    int*   bucket_cnt    = (int*)p;   p += (size_t)512 * 4;
    int*   bucket_base   = (int*)p;   p += (size_t)512 * 4;
    int*   bucket_cursor = (int*)p;   p += (size_t)512 * 4;
    int*   rowptr        = (int*)p;   p += (size_t)(N + 1) * 4;
    int*   csr           = (int*)p;   p += (size_t)E * 4;
    unsigned int* binned = (unsigned int*)p; p += (size_t)E * 4;
    float* dis    = (float*)p; p += (size_t)N * 4;
    float* qA     = (float*)p; p += (size_t)N * 4;
    float* qB     = (float*)p; p += (size_t)N * 4;
    float* vacc   = (float*)p; p += (size_t)N * 4;
    float* c      = (float*)p; p += (size_t)8 * 4;
    float* bmin   = (float*)p; p += (size_t)gblocks * 4;
    float* bmax   = (float*)p; p += (size_t)gblocks * 4;
    float* mnmx   = (float*)p; p += 2 * 4;

    // ---- CSR build + coefficients (coef hidden in hist launch) ----
    hipMemsetAsync(bucket_cnt, 0, 512 * 4, stream);
    const int nbh = 128;                  // 1024-thread hist blocks
    hist_coef_kernel<<<nbh + 1, HTPB, 0, stream>>>(dst, E, bucket_cnt, nb,
                                                   W1, b1, W2, b2, W3, b3,
                                                   W4, b4, W5, b5, W6, b6, c);
    bucket_scan<<<1, 512, 0, stream>>>(bucket_cnt, nb, bucket_base, bucket_cursor,
                                       rowptr, N, E);
    binA_kernel<<<cdiv(E, BINE), 256, 0, stream>>>(src, dst, E, bucket_cursor, binned);
    csrB_kernel<<<nb, 256, 0, stream>>>(binned, bucket_base, N, rowptr, csr, dis);

    // ---- gather chain: coop<7,1024> if 4 blocks/CU fit, else launch chain ----
    constexpr int CB7 = 1024, NS7 = 7;
    int occ = 0;
    hipError_t oerr = hipOccupancyMaxActiveBlocksPerMultiprocessor(
        &occ, (const void*)coop_gather_t<NS7, CB7>, 256, 0);
    bool canCoop = (oerr == hipSuccess) && ((long long)occ * 256 >= CB7) &&
                   (N <= CB7 * 16 * NS7);
    if (canCoop) {
        const int* rp = rowptr; const int* cs = csr;
        const float* dis_c = dis; const float* cc = c;
        float* qA_ = qA; float* qB_ = qB;
        float* bmin_ = bmin; float* bmax_ = bmax;
        float* outp = (float*)d_out;
        int n_ = N;
        void* args[] = { &rp, &cs, &dis_c, &qA_, &qB_, &cc, &bmin_, &bmax_, &outp, &n_ };
        hipLaunchCooperativeKernel((const void*)coop_gather_t<NS7, CB7>,
                                   dim3(CB7), dim3(256), args, 0, stream);
    } else {
        gather_step<<<gblocks, TPB, 0, stream>>>(rowptr, csr, dis, dis, c, 1, qA, vacc, N, 1);
        gather_step<<<gblocks, TPB, 0, stream>>>(rowptr, csr, dis, qA,  c, 2, qB, vacc, N, 0);
        gather_step<<<gblocks, TPB, 0, stream>>>(rowptr, csr, dis, qB,  c, 3, qA, vacc, N, 0);
        gather_step<<<gblocks, TPB, 0, stream>>>(rowptr, csr, dis, qA,  c, 4, qB, vacc, N, 0);
        gather_step<<<gblocks, TPB, 0, stream>>>(rowptr, csr, dis, qB,  c, 5, qA, vacc, N, 0);
        gather_last<<<gblocks, TPB, 0, stream>>>(rowptr, csr, dis, qA, c, vacc, bmin, bmax, N);
        minmax_final_kernel<<<1, TPB, 0, stream>>>(bmin, bmax, gblocks, mnmx);
        normalize_kernel<<<cdiv(N, TPB), TPB, 0, stream>>>(vacc, mnmx, (float*)d_out, N);
    }
}

// Round 12
// 172.449 us; speedup vs baseline: 3.2741x; 1.0535x over previous
//
#include <hip/hip_runtime.h>
#include <hip/hip_cooperative_groups.h>

namespace cg = cooperative_groups;

// GCN 6-layer, N=100k, E=3.2M — Krylov form + binned CSR build.
// v = sum_{k=0..6} c_k * p_k, p_k = A_norm^k 1.
// Round 12: coop_gather_t gets __launch_bounds__(256,4) so the NS=7/CB=1024
// geometry actually fits 4 blocks/CU (R10/R11 gate silently failed: no
// launch-bounds -> >128 VGPR -> occ<4 -> chain fallback). csrB int4 reads.

#define TPB 256
#define HTPB 1024        // hist_coef block size
#define NBPAD 400        // >= nb=391 buckets
#define BINE 8192        // edges per binA block
#define STAGE_CAP 12288  // per-bucket csr LDS stage (mean 8192, sigma ~90)
#define IDXC 4           // cached csr entries per lane (deg <= 64 fast path)

// ---------- coefficient chain helper: 8-way i-split, 1024 threads ----------
template <int NK, int DIN>
__device__ void coef_step8(const float* __restrict__ W, const float* __restrict__ bias,
                           const float (*in)[128], float (*out)[128],
                           float (*part)[6][128], int tid) {
    int t = tid & 127, g = tid >> 7;          // 8 i-groups
    const int CH = (DIN + 7) / 8;
    int i0 = g * CH; if (i0 > DIN) i0 = DIN;
    int i1 = i0 + CH; if (i1 > DIN) i1 = DIN;
    float s[NK];
#pragma unroll
    for (int k = 0; k < NK; ++k) s[k] = 0.f;
    if (t < 125) {
#pragma unroll 4
        for (int i = i0; i < i1; ++i) {
            float w = W[i * 125 + t];
#pragma unroll
            for (int k = 0; k < NK; ++k) s[k] += w * in[k][i];
        }
    }
#pragma unroll
    for (int k = 0; k < NK; ++k) part[g][k][t] = s[k];
    __syncthreads();
    if (g == 0 && t < 125) {
#pragma unroll
        for (int k = 0; k < NK; ++k) {
            float acc = part[0][k][t];
#pragma unroll
            for (int gg = 1; gg < 8; ++gg) acc += part[gg][k][t];
            out[k + 1][t] = acc;
        }
        out[0][t] = bias[t];
    }
    __syncthreads();
}

// ---------- merged histogram + coefficient kernel (1024 threads) ----------
__global__ __launch_bounds__(HTPB) void hist_coef_kernel(
    const int* __restrict__ dst, int E, int* __restrict__ bucket_cnt, int nb,
    const float* __restrict__ W1, const float* __restrict__ b1,
    const float* __restrict__ W2, const float* __restrict__ b2,
    const float* __restrict__ W3, const float* __restrict__ b3,
    const float* __restrict__ W4, const float* __restrict__ b4,
    const float* __restrict__ W5, const float* __restrict__ b5,
    const float* __restrict__ W6, const float* __restrict__ b6,
    float* __restrict__ c) {
    __shared__ int h[NBPAD];
    __shared__ float A[6][128];
    __shared__ float B[6][128];
    __shared__ float part[8][6][128];
    int tid = threadIdx.x;
    int nbh = gridDim.x - 1;

    if ((int)blockIdx.x < nbh) {
        for (int j = tid; j < NBPAD; j += HTPB) h[j] = 0;
        __syncthreads();
        const int E4 = E >> 2;
        const int chunk4 = (E4 + nbh - 1) / nbh;
        const int b4 = (int)blockIdx.x * chunk4;
        const int e4 = (b4 + chunk4 < E4) ? (b4 + chunk4) : E4;
        const int4* d4 = (const int4*)dst;
        for (int j = b4 + tid; j < e4; j += HTPB) {
            int4 v = d4[j];
            atomicAdd(&h[v.x >> 8], 1);
            atomicAdd(&h[v.y >> 8], 1);
            atomicAdd(&h[v.z >> 8], 1);
            atomicAdd(&h[v.w >> 8], 1);
        }
        if (blockIdx.x == 0) {  // scalar tail (E % 4)
            for (int j = (E4 << 2) + tid; j < E; j += HTPB) atomicAdd(&h[dst[j] >> 8], 1);
        }
        __syncthreads();
        for (int j = tid; j < nb; j += HTPB)
            if (h[j]) atomicAdd(&bucket_cnt[j], h[j]);
        return;
    }

    // coefficient chain (8-way i-split)
    if (tid < 25) { A[1][tid] = W1[tid]; A[0][tid] = b1[tid]; }
    __syncthreads();
    coef_step8<2, 25>(W2, b2, A, B, part, tid);
    coef_step8<3, 125>(W3, b3, B, A, part, tid);
    coef_step8<4, 125>(W4, b4, A, B, part, tid);
    coef_step8<5, 125>(W5, b5, B, A, part, tid);
    // layer 6: c[k+1] = W6 . A[k]; waves 0..5 each handle one k
    int wave = tid >> 6, lane = tid & 63;
    if (wave < 6) {
        int k = wave;
        float acc = (lane < 125 ? W6[lane] * A[k][lane] : 0.f)
                  + (lane + 64 < 125 ? W6[lane + 64] * A[k][lane + 64] : 0.f);
        for (int off = 32; off > 0; off >>= 1) acc += __shfl_down(acc, off);
        if (lane == 0) c[k + 1] = acc;
    }
    if (tid == 0) c[0] = b6[0];
}

// exclusive scan of nb (<512) bucket counts; init base + cursor; rowptr[n]=E
__global__ void bucket_scan(const int* __restrict__ bucket_cnt, int nb,
                            int* __restrict__ bucket_base, int* __restrict__ bucket_cursor,
                            int* __restrict__ rowptr, int n, int E) {
    __shared__ int s[512];
    int t = threadIdx.x;
    int v = (t < nb) ? bucket_cnt[t] : 0;
    s[t] = v;
    __syncthreads();
    for (int off = 1; off < 512; off <<= 1) {
        int a = (t >= off) ? s[t - off] : 0;
        __syncthreads();
        s[t] += a;
        __syncthreads();
    }
    if (t < nb) {
        int ex = s[t] - v;
        bucket_base[t] = ex;
        bucket_cursor[t] = ex;
    }
    if (t == 0) { bucket_base[nb] = E; rowptr[n] = E; }
}

// ---------- binA: LDS-staged counting sort per 8192-edge block ----------
// binned word: (dst&255)<<24 | src   (src < 2^24)
__global__ __launch_bounds__(256) void binA_kernel(
    const int* __restrict__ src, const int* __restrict__ dst, int E,
    int* __restrict__ bucket_cursor, unsigned int* __restrict__ binned) {
    __shared__ int cnt[NBPAD];
    __shared__ int sa[512], sb[512];
    __shared__ int lbase[NBPAD];
    __shared__ int gbase[NBPAD];
    __shared__ int lcur[NBPAD];
    __shared__ unsigned int stagew[BINE];
    __shared__ unsigned short sbuck[BINE];
    int t = threadIdx.x;
    long long base = (long long)blockIdx.x * BINE;
    int ne = (E - base < BINE) ? (int)(E - base) : BINE;

    for (int j = t; j < NBPAD; j += 256) cnt[j] = 0;
    __syncthreads();

    // count phase: int4 loads, dst cached in registers
    int dv[8][4];
    const int4* d4 = (const int4*)(dst + base);
#pragma unroll
    for (int i = 0; i < 8; ++i) {
        int j4 = t + i * 256;
        if ((j4 << 2) + 3 < ne) {
            int4 v = d4[j4];
            dv[i][0] = v.x; dv[i][1] = v.y; dv[i][2] = v.z; dv[i][3] = v.w;
        } else {
#pragma unroll
            for (int cx = 0; cx < 4; ++cx) {
                int j = (j4 << 2) + cx;
                dv[i][cx] = (j < ne) ? dst[base + j] : -1;
            }
        }
#pragma unroll
        for (int cx = 0; cx < 4; ++cx)
            if (dv[i][cx] >= 0) atomicAdd(&cnt[dv[i][cx] >> 8], 1);
    }
    __syncthreads();
    // Kogge-Stone inclusive scan over 512 (ping-pong)
    for (int j = t; j < 512; j += 256) sa[j] = (j < NBPAD) ? cnt[j] : 0;
    __syncthreads();
    int* cu = sa; int* nx = sb;
    for (int off = 1; off < 512; off <<= 1) {
        for (int j = t; j < 512; j += 256) nx[j] = cu[j] + (j >= off ? cu[j - off] : 0);
        __syncthreads();
        int* tmp = cu; cu = nx; nx = tmp;
    }
    for (int j = t; j < NBPAD; j += 256) {
        int ex = cu[j] - cnt[j];
        lbase[j] = ex;
        lcur[j] = ex;
        gbase[j] = cnt[j] ? atomicAdd(&bucket_cursor[j], cnt[j]) : 0;
    }
    __syncthreads();
    // stage phase: int4 src loads, dst from registers
    const int4* s4 = (const int4*)(src + base);
#pragma unroll
    for (int i = 0; i < 8; ++i) {
        int j4 = t + i * 256;
        int sv[4];
        if ((j4 << 2) + 3 < ne) {
            int4 v = s4[j4];
            sv[0] = v.x; sv[1] = v.y; sv[2] = v.z; sv[3] = v.w;
        } else {
#pragma unroll
            for (int cx = 0; cx < 4; ++cx) {
                int j = (j4 << 2) + cx;
                sv[cx] = (j < ne) ? src[base + j] : -1;
            }
        }
#pragma unroll
        for (int cx = 0; cx < 4; ++cx) {
            if (dv[i][cx] >= 0) {
                int bk = dv[i][cx] >> 8;
                int pos = atomicAdd(&lcur[bk], 1);
                stagew[pos] = ((unsigned)(dv[i][cx] & 255) << 24) | (unsigned)sv[cx];
                sbuck[pos] = (unsigned short)bk;
            }
        }
    }
    __syncthreads();
    // coalesced chunk flush
    for (int j = t; j < ne; j += 256) {
        int bk = sbuck[j];
        binned[gbase[bk] + (j - lbase[bk])] = stagew[j];
    }
}

// ---------- csrB: one block per bucket -> rowptr, dis, node-sorted csr ----------
__global__ __launch_bounds__(256) void csrB_kernel(
    const unsigned int* __restrict__ binned,
    const int* __restrict__ bucket_base, int n,
    int* __restrict__ rowptr, int* __restrict__ csr, float* __restrict__ dis) {
    __shared__ int deg[256];
    __shared__ int ex[256];
    __shared__ int cur[256];
    __shared__ int stage[STAGE_CAP];
    int b = blockIdx.x;
    int t = threadIdx.x;
    int ebase = bucket_base[b], eend = bucket_base[b + 1];
    int esize = eend - ebase;
    int gnode = (b << 8) + t;
    deg[t] = 0;
    __syncthreads();
    // int4-vectorized deg count: scalar head to 4-alignment, vector mid, tail
    int a0 = (ebase + 3) & ~3; if (a0 > eend) a0 = eend;
    int a1 = eend & ~3;        if (a1 < a0) a1 = a0;
    for (int e = ebase + t; e < a0; e += 256) atomicAdd(&deg[binned[e] >> 24], 1);
    {
        const uint4* b4 = (const uint4*)(binned + a0);
        int n4 = (a1 - a0) >> 2;
        for (int j = t; j < n4; j += 256) {
            uint4 v = b4[j];
            atomicAdd(&deg[v.x >> 24], 1);
            atomicAdd(&deg[v.y >> 24], 1);
            atomicAdd(&deg[v.z >> 24], 1);
            atomicAdd(&deg[v.w >> 24], 1);
        }
    }
    for (int e = a1 + t; e < eend; e += 256) atomicAdd(&deg[binned[e] >> 24], 1);
    __syncthreads();
    int d = deg[t];
    ex[t] = d;
    __syncthreads();
    for (int off = 1; off < 256; off <<= 1) {
        int a = (t >= off) ? ex[t - off] : 0;
        __syncthreads();
        ex[t] += a;
        __syncthreads();
    }
    int excl = ex[t] - d;
    if (gnode < n) {
        rowptr[gnode] = ebase + excl;
        dis[gnode] = rsqrtf((float)d + 1.0f);   // +1 = self-loop
    }
    cur[t] = excl;
    __syncthreads();
    if (esize <= STAGE_CAP) {
        // int4-vectorized scatter into LDS stage
        for (int e = ebase + t; e < a0; e += 256) {
            unsigned int pk = binned[e];
            stage[atomicAdd(&cur[pk >> 24], 1)] = (int)(pk & 0xffffffu);
        }
        {
            const uint4* b4 = (const uint4*)(binned + a0);
            int n4 = (a1 - a0) >> 2;
            for (int j = t; j < n4; j += 256) {
                uint4 v = b4[j];
                stage[atomicAdd(&cur[v.x >> 24], 1)] = (int)(v.x & 0xffffffu);
                stage[atomicAdd(&cur[v.y >> 24], 1)] = (int)(v.y & 0xffffffu);
                stage[atomicAdd(&cur[v.z >> 24], 1)] = (int)(v.z & 0xffffffu);
                stage[atomicAdd(&cur[v.w >> 24], 1)] = (int)(v.w & 0xffffffu);
            }
        }
        for (int e = a1 + t; e < eend; e += 256) {
            unsigned int pk = binned[e];
            stage[atomicAdd(&cur[pk >> 24], 1)] = (int)(pk & 0xffffffu);
        }
        __syncthreads();
        for (int e = t; e < esize; e += 256) csr[ebase + e] = stage[e];
    } else {  // statistical-impossibility fallback, keeps any input correct
        for (int e = ebase + t; e < eend; e += 256) {
            unsigned int pk = binned[e];
            int pos = atomicAdd(&cur[pk >> 24], 1);
            csr[ebase + pos] = (int)(pk & 0xffffffu);
        }
    }
}

// ---------- cooperative fused gather chain (templated geometry) ----------
// NS sweeps, CBT blocks x 256 threads; __launch_bounds__(256,4) forces the
// register allocation to fit 4 blocks/CU (1024 co-resident blocks).
template <int NS, int CBT>
__global__ __launch_bounds__(256, 4) void coop_gather_t(
    const int* __restrict__ rowptr, const int* __restrict__ csr,
    const float* __restrict__ dis, float* __restrict__ qA, float* __restrict__ qB,
    const float* __restrict__ c,
    float* __restrict__ bmin, float* __restrict__ bmax,
    float* __restrict__ out, int n) {
    cg::grid_group grid = cg::this_grid();
    __shared__ float smn[256], smx[256];
    int t = threadIdx.x;
    int lane = t & 15, grp = t >> 4;
    int gid0 = (int)blockIdx.x * 16 + grp;       // node id at sweep 0, stride CBT*16

    int beg[NS], end[NS];
    int idx[NS][IDXC];
    float dd[NS], qown[NS], vacc[NS];
    float cc[7];
#pragma unroll
    for (int k = 0; k < 7; ++k) cc[k] = c[k];

    // prefetch graph into registers (csr read ONCE for deg<=64)
#pragma unroll
    for (int s = 0; s < NS; ++s) {
        int node = gid0 + s * (CBT * 16);
        bool act = node < n;
        beg[s] = act ? rowptr[node] : 0;
        end[s] = act ? rowptr[node + 1] : 0;
        dd[s]  = act ? dis[node] : 0.f;
        qown[s] = dd[s];                 // q0 = dis .* ones
        vacc[s] = cc[0];
#pragma unroll
        for (int j = 0; j < IDXC; ++j) {
            int e = beg[s] + lane + j * 16;
            idx[s][j] = (e < end[s]) ? csr[e] : -1;
        }
    }

    const float* q = dis;
    for (int k = 1; k <= 6; ++k) {
        float* qn = (k & 1) ? qA : qB;
#pragma unroll
        for (int s = 0; s < NS; ++s) {
            float acc = 0.f;
#pragma unroll
            for (int j = 0; j < IDXC; ++j)
                if (idx[s][j] >= 0) acc += q[idx[s][j]];
            for (int e = beg[s] + IDXC * 16 + lane; e < end[s]; e += 16)
                acc += q[csr[e]];        // deg > 64 tail (statistically ~never)
#pragma unroll
            for (int off = 8; off > 0; off >>= 1) acc += __shfl_down(acc, off, 16);
            int node = gid0 + s * (CBT * 16);
            if (lane == 0 && node < n) {
                float p = dd[s] * (acc + qown[s]);
                qown[s] = dd[s] * p;
                if (k < 6) qn[node] = qown[s];
                vacc[s] += cc[k] * p;
            }
        }
        if (k < 6) {
            __threadfence();
            grid.sync();
            q = qn;
        }
    }

    // block-local min/max of vacc (lane0s hold real values)
    float mn = 1e30f, mx = -1e30f;
    if (lane == 0) {
#pragma unroll
        for (int s = 0; s < NS; ++s) {
            int node = gid0 + s * (CBT * 16);
            if (node < n) { mn = fminf(mn, vacc[s]); mx = fmaxf(mx, vacc[s]); }
        }
    }
    smn[t] = mn; smx[t] = mx;
    __syncthreads();
    for (int sft = 128; sft > 0; sft >>= 1) {
        if (t < sft) {
            smn[t] = fminf(smn[t], smn[t + sft]);
            smx[t] = fmaxf(smx[t], smx[t + sft]);
        }
        __syncthreads();
    }
    if (t == 0) { bmin[blockIdx.x] = smn[0]; bmax[blockIdx.x] = smx[0]; }
    __threadfence();
    grid.sync();

    // redundant per-block final reduce + normalize
    mn = 1e30f; mx = -1e30f;
    for (int j = t; j < CBT; j += 256) {
        mn = fminf(mn, bmin[j]);
        mx = fmaxf(mx, bmax[j]);
    }
    smn[t] = mn; smx[t] = mx;
    __syncthreads();
    for (int sft = 128; sft > 0; sft >>= 1) {
        if (t < sft) {
            smn[t] = fminf(smn[t], smn[t + sft]);
            smx[t] = fmaxf(smx[t], smx[t + sft]);
        }
        __syncthreads();
    }
    mn = smn[0]; mx = smx[0];
    float inv = 1.0f / (mx - mn + 1e-15f);
    if (lane == 0) {
#pragma unroll
        for (int s = 0; s < NS; ++s) {
            int node = gid0 + s * (CBT * 16);
            if (node < n) out[node] = (vacc[s] - mn) * inv;
        }
    }
}

// ---------- fallback chain (round-8, known-good) ----------
__global__ void gather_step(const int* __restrict__ rowptr, const int* __restrict__ csr,
                            const float* __restrict__ dis, const float* __restrict__ q,
                            const float* __restrict__ c, int k,
                            float* __restrict__ qnext, float* __restrict__ vacc,
                            int n, int first) {
    int tid = blockIdx.x * blockDim.x + threadIdx.x;
    int node = tid >> 4;
    int lane = tid & 15;
    if (node >= n) return;
    int beg = rowptr[node], end = rowptr[node + 1];
    float acc = 0.f;
    for (int e = beg + lane; e < end; e += 16) acc += q[csr[e]];
    for (int off = 8; off > 0; off >>= 1) acc += __shfl_down(acc, off, 16);
    if (lane == 0) {
        float d = dis[node];
        float p = d * (acc + q[node]);
        qnext[node] = d * p;
        float add = c[k] * p;
        vacc[node] = first ? (c[0] + add) : (vacc[node] + add);
    }
}

__global__ void gather_last(const int* __restrict__ rowptr, const int* __restrict__ csr,
                            const float* __restrict__ dis, const float* __restrict__ q,
                            const float* __restrict__ c,
                            float* __restrict__ vacc,
                            float* __restrict__ bmin, float* __restrict__ bmax, int n) {
    __shared__ float smn[TPB], smx[TPB];
    int t = threadIdx.x;
    int tid = blockIdx.x * blockDim.x + t;
    int node = tid >> 4;
    int lane = tid & 15;
    float v = 1e30f;
    bool act = (node < n);
    if (act) {
        int beg = rowptr[node], end = rowptr[node + 1];
        float acc = 0.f;
        for (int e = beg + lane; e < end; e += 16) acc += q[csr[e]];
        for (int off = 8; off > 0; off >>= 1) acc += __shfl_down(acc, off, 16);
        if (lane == 0) {
            float d = dis[node];
            float p = d * (acc + q[node]);
            v = vacc[node] + c[6] * p;
            vacc[node] = v;
        }
    }
    smn[t] = (act && lane == 0) ? v : 1e30f;
    smx[t] = (act && lane == 0) ? v : -1e30f;
    __syncthreads();
    for (int s = TPB / 2; s > 0; s >>= 1) {
        if (t < s) { smn[t] = fminf(smn[t], smn[t + s]); smx[t] = fmaxf(smx[t], smx[t + s]); }
        __syncthreads();
    }
    if (t == 0) { bmin[blockIdx.x] = smn[0]; bmax[blockIdx.x] = smx[0]; }
}

__global__ void minmax_final_kernel(const float* __restrict__ bmin, const float* __restrict__ bmax,
                                    int nblk, float* __restrict__ mnmx) {
    __shared__ float smn[TPB], smx[TPB];
    int t = threadIdx.x;
    float mn = 1e30f, mx = -1e30f;
    for (int i = t; i < nblk; i += TPB) {
        mn = fminf(mn, bmin[i]);
        mx = fmaxf(mx, bmax[i]);
    }
    smn[t] = mn; smx[t] = mx;
    __syncthreads();
    for (int s = TPB / 2; s > 0; s >>= 1) {
        if (t < s) { smn[t] = fminf(smn[t], smn[t + s]); smx[t] = fmaxf(smx[t], smx[t + s]); }
        __syncthreads();
    }
    if (t == 0) { mnmx[0] = smn[0]; mnmx[1] = smx[0]; }
}

__global__ void normalize_kernel(const float* __restrict__ v, const float* __restrict__ mnmx,
                                 float* __restrict__ out, int n) {
    int i = blockIdx.x * blockDim.x + threadIdx.x;
    if (i < n) {
        float mn = mnmx[0], mx = mnmx[1];
        out[i] = (v[i] - mn) / (mx - mn + 1e-15f);
    }
}

static inline int cdiv(long long a, int b) { return (int)((a + b - 1) / b); }

extern "C" void kernel_launch(void* const* d_in, const int* in_sizes, int n_in,
                              void* d_out, int out_size, void* d_ws, size_t ws_size,
                              hipStream_t stream) {
    const int N = out_size;               // 100000
    const int E = in_sizes[0] / 2;        // 3200000
    const int* src = (const int*)d_in[0];
    const int* dst = src + E;

    const float* W1 = (const float*)d_in[1];  const float* b1 = (const float*)d_in[2];
    const float* W2 = (const float*)d_in[3];  const float* b2 = (const float*)d_in[4];
    const float* W3 = (const float*)d_in[5];  const float* b3 = (const float*)d_in[6];
    const float* W4 = (const float*)d_in[7];  const float* b4 = (const float*)d_in[8];
    const float* W5 = (const float*)d_in[9];  const float* b5 = (const float*)d_in[10];
    const float* W6 = (const float*)d_in[11]; const float* b6 = (const float*)d_in[12];

    const int nb = (N + 255) >> 8;        // 391 buckets of 256 nodes
    const int gblocks = cdiv((long long)N * 16, TPB);   // 6250

    // workspace layout
    char* p = (char*)d_ws;
    int*   bucket_cnt    = (int*)p;   p += (size_t)512 * 4;
    int*   bucket_base   = (int*)p;   p += (size_t)512 * 4;
    int*   bucket_cursor = (int*)p;   p += (size_t)512 * 4;
    int*   rowptr        = (int*)p;   p += (size_t)(N + 1) * 4;
    int*   csr           = (int*)p;   p += (size_t)E * 4;
    unsigned int* binned = (unsigned int*)p; p += (size_t)E * 4;
    float* dis    = (float*)p; p += (size_t)N * 4;
    float* qA     = (float*)p; p += (size_t)N * 4;
    float* qB     = (float*)p; p += (size_t)N * 4;
    float* vacc   = (float*)p; p += (size_t)N * 4;
    float* c      = (float*)p; p += (size_t)8 * 4;
    float* bmin   = (float*)p; p += (size_t)gblocks * 4;
    float* bmax   = (float*)p; p += (size_t)gblocks * 4;
    float* mnmx   = (float*)p; p += 2 * 4;

    // ---- CSR build + coefficients (coef hidden in hist launch) ----
    hipMemsetAsync(bucket_cnt, 0, 512 * 4, stream);
    const int nbh = 128;                  // 1024-thread hist blocks
    hist_coef_kernel<<<nbh + 1, HTPB, 0, stream>>>(dst, E, bucket_cnt, nb,
                                                   W1, b1, W2, b2, W3, b3,
                                                   W4, b4, W5, b5, W6, b6, c);
    bucket_scan<<<1, 512, 0, stream>>>(bucket_cnt, nb, bucket_base, bucket_cursor,
                                       rowptr, N, E);
    binA_kernel<<<cdiv(E, BINE), 256, 0, stream>>>(src, dst, E, bucket_cursor, binned);
    csrB_kernel<<<nb, 256, 0, stream>>>(binned, bucket_base, N, rowptr, csr, dis);

    // ---- gather chain: coop<7,1024> if 4 blocks/CU fit, else launch chain ----
    constexpr int CB7 = 1024, NS7 = 7;
    int occ = 0;
    hipError_t oerr = hipOccupancyMaxActiveBlocksPerMultiprocessor(
        &occ, (const void*)coop_gather_t<NS7, CB7>, 256, 0);
    bool canCoop = (oerr == hipSuccess) && ((long long)occ * 256 >= CB7) &&
                   (N <= CB7 * 16 * NS7);
    if (canCoop) {
        const int* rp = rowptr; const int* cs = csr;
        const float* dis_c = dis; const float* cc = c;
        float* qA_ = qA; float* qB_ = qB;
        float* bmin_ = bmin; float* bmax_ = bmax;
        float* outp = (float*)d_out;
        int n_ = N;
        void* args[] = { &rp, &cs, &dis_c, &qA_, &qB_, &cc, &bmin_, &bmax_, &outp, &n_ };
        hipLaunchCooperativeKernel((const void*)coop_gather_t<NS7, CB7>,
                                   dim3(CB7), dim3(256), args, 0, stream);
    } else {
        gather_step<<<gblocks, TPB, 0, stream>>>(rowptr, csr, dis, dis, c, 1, qA, vacc, N, 1);
        gather_step<<<gblocks, TPB, 0, stream>>>(rowptr, csr, dis, qA,  c, 2, qB, vacc, N, 0);
        gather_step<<<gblocks, TPB, 0, stream>>>(rowptr, csr, dis, qB,  c, 3, qA, vacc, N, 0);
        gather_step<<<gblocks, TPB, 0, stream>>>(rowptr, csr, dis, qA,  c, 4, qB, vacc, N, 0);
        gather_step<<<gblocks, TPB, 0, stream>>>(rowptr, csr, dis, qB,  c, 5, qA, vacc, N, 0);
        gather_last<<<gblocks, TPB, 0, stream>>>(rowptr, csr, dis, qA, c, vacc, bmin, bmax, N);
        minmax_final_kernel<<<1, TPB, 0, stream>>>(bmin, bmax, gblocks, mnmx);
        normalize_kernel<<<cdiv(N, TPB), TPB, 0, stream>>>(vacc, mnmx, (float*)d_out, N);
    }
}